// Round 2
// baseline (17079.472 us; speedup 1.0000x reference)
//
#include <hip/hip_runtime.h>
#include <hip/hip_bf16.h>
#include <math.h>

// GGNN: L=5 layers of { m = h@W_l ; agg = scatter_add(ew * m[src] -> dst) ;
//                       h = GRUCell(agg, h) } then out = relu(h)@fc_w^T + fc_b
// H=256, N=50000, E=800000.
//
// Workspace budget is the Round-1 lesson: keep it minimal. Layout is
// 3 x [N,256] f32 buffers + ~3MB of converted weights ~= 150 MiB.
// The GRU gate GEMMs are fused with the pointwise GRU update (no [N,1024]
// gate buffer is ever materialized).
//
// Float inputs may be bf16 (harness-converted) or f32; edge_index may be
// int32 or int64. Detected on-device (graph-safe, identical work per call).

#define HDIM 256

__device__ __forceinline__ float ldf(const void* p, size_t i, int isbf) {
    if (isbf) return __bfloat162float(((const __hip_bfloat16*)p)[i]);
    return ((const float*)p)[i];
}

// flags[0] = 1 if float tensors are bf16, 0 if f32
// flags[1] = 1 if edge_index is int64, 0 if int32
__global__ void detect_k(const void* x, const void* ei, int* flags) {
    if (blockIdx.x == 0 && threadIdx.x == 0) {
        const __hip_bfloat16* xb = (const __hip_bfloat16*)x;
        int isbf = 1;
        for (int i = 0; i < 1024; ++i) {
            float v = fabsf(__bfloat162float(xb[i]));
            if (!(v < 1e6f)) { isbf = 0; break; }  // f32 read as bf16 -> huge/NaN
        }
        flags[0] = isbf;
        const int* e32 = (const int*)ei;
        int orv = e32[1] | e32[3] | e32[5] | e32[7] | e32[9] | e32[11];
        flags[1] = (orv == 0) ? 1 : 0;  // int64: high words all zero
    }
}

__global__ void convert_x_k(const void* x, float* h, const int* flags, size_t n) {
    size_t i = (size_t)blockIdx.x * blockDim.x + threadIdx.x;
    if (i < n) h[i] = ldf(x, i, flags[0]);
}

// Wt[l][j][k] = weight[l][k][j] (so the layer GEMM is NT form).
// Wih/Whh: [768][256] f32 copies of w_ih/w_hh (gate order r,z,n).
// bsum[512] = b_ih+b_hh for r,z; bni[256] = b_ih_n; bnh[256] = b_hh_n.
__global__ void prep_k(const void* w, const void* wih, const void* whh,
                       const void* bih, const void* bhh,
                       float* Wt, float* Wih, float* Whh,
                       float* bsum, float* bni, float* bnh,
                       const int* flags, int L) {
    int i = blockIdx.x * blockDim.x + threadIdx.x;
    int isbf = flags[0];
    if (i < L * 65536) {
        int l = i >> 16, rem = i & 65535;
        int j = rem >> 8, k = rem & 255;
        Wt[i] = ldf(w, ((size_t)l << 16) + (size_t)k * 256 + j, isbf);
    }
    if (i < 196608) {
        Wih[i] = ldf(wih, i, isbf);
        Whh[i] = ldf(whh, i, isbf);
    }
    if (i < 512) bsum[i] = ldf(bih, i, isbf) + ldf(bhh, i, isbf);
    if (i < 256) {
        bni[i] = ldf(bih, 512 + i, isbf);
        bnh[i] = ldf(bhh, 512 + i, isbf);
    }
}

__global__ void zero_k(float4* p, size_t n4) {
    size_t i = (size_t)blockIdx.x * blockDim.x + threadIdx.x;
    if (i < n4) p[i] = make_float4(0.f, 0.f, 0.f, 0.f);
}

// C[M,256] = A[M,256] @ B[256,256]^T. 64x64 tile / 256-thread block, BK=16,
// k-major LDS (68-float rows keep 16B alignment + kill >2-way conflicts),
// 4x4 acc per thread.
__global__ __launch_bounds__(256)
void gemm1_k(const float* __restrict__ A, const float* __restrict__ B,
             float* __restrict__ C, int M) {
    __shared__ __align__(16) float As[16][68];
    __shared__ __align__(16) float Bs[16][68];
    const int tid = threadIdx.x;
    const int row0 = blockIdx.x * 64, col0 = blockIdx.y * 64;
    const int lr = tid >> 2;
    const int lk = (tid & 3) << 2;
    const int ty = tid >> 4, tx = tid & 15;
    float acc[4][4];
#pragma unroll
    for (int i = 0; i < 4; ++i)
#pragma unroll
        for (int j = 0; j < 4; ++j) acc[i][j] = 0.f;

    for (int kc = 0; kc < 256; kc += 16) {
        __syncthreads();
        {
            const int grow = row0 + lr;
            float4 av = make_float4(0.f, 0.f, 0.f, 0.f);
            if (grow < M) av = *(const float4*)&A[(size_t)grow * 256 + kc + lk];
            const float4 bv = *(const float4*)&B[(size_t)(col0 + lr) * 256 + kc + lk];
            As[lk + 0][lr] = av.x; As[lk + 1][lr] = av.y;
            As[lk + 2][lr] = av.z; As[lk + 3][lr] = av.w;
            Bs[lk + 0][lr] = bv.x; Bs[lk + 1][lr] = bv.y;
            Bs[lk + 2][lr] = bv.z; Bs[lk + 3][lr] = bv.w;
        }
        __syncthreads();
#pragma unroll
        for (int kk = 0; kk < 16; ++kk) {
            const float4 a = *(const float4*)&As[kk][ty << 2];
            const float4 b = *(const float4*)&Bs[kk][tx << 2];
            const float ar[4] = {a.x, a.y, a.z, a.w};
            const float br[4] = {b.x, b.y, b.z, b.w};
#pragma unroll
            for (int i = 0; i < 4; ++i)
#pragma unroll
                for (int j = 0; j < 4; ++j) acc[i][j] = fmaf(ar[i], br[j], acc[i][j]);
        }
    }
#pragma unroll
    for (int i = 0; i < 4; ++i) {
        const int row = row0 + (ty << 2) + i;
        if (row < M) {
            float4 v;
            v.x = acc[i][0]; v.y = acc[i][1]; v.z = acc[i][2]; v.w = acc[i][3];
            *(float4*)&C[(size_t)row * 256 + col0 + (tx << 2)] = v;
        }
    }
}

// One wave per edge: coalesced float4 gather of m[src], 4 atomicAdds into agg[dst].
__global__ void scatter_k(const float* __restrict__ m, const void* ei, const void* ew,
                          float* __restrict__ agg, const int* flags, int E) {
    const int e = blockIdx.x * 4 + (threadIdx.x >> 6);
    if (e >= E) return;
    const int lane = threadIdx.x & 63;
    const int* e32 = (const int*)ei;
    int s, d;
    if (flags[1]) { s = e32[2 * (size_t)e]; d = e32[2 * ((size_t)E + e)]; }
    else          { s = e32[e];             d = e32[(size_t)E + e]; }
    const float w = ldf(ew, e, flags[0]);
    const float4 v = *(const float4*)&m[(size_t)s * HDIM + (lane << 2)];
    float* ap = &agg[(size_t)d * HDIM + (lane << 2)];
    atomicAdd(ap + 0, w * v.x);
    atomicAdd(ap + 1, w * v.y);
    atomicAdd(ap + 2, w * v.z);
    atomicAdd(ap + 3, w * v.w);
}

// Fused GRU gate GEMMs + pointwise update. Block = 64 node-rows x 64 hidden
// cols; computes the 4 needed gate strips (r,z with both operands summed
// in-flight; n_i from agg@Wih_n; n_h from hold@Whh_n), then
// h_new = (1-z)*tanh(n_i + r*n_h) + z*h_old. No [N,1024] buffer.
__global__ __launch_bounds__(256)
void gates_gru_k(const float* __restrict__ agg, const float* __restrict__ hold,
                 const float* __restrict__ Wih, const float* __restrict__ Whh,
                 const float* __restrict__ bsum, const float* __restrict__ bni,
                 const float* __restrict__ bnh,
                 float* __restrict__ hnew, int N) {
    __shared__ __align__(16) float Aa[16][68];
    __shared__ __align__(16) float Ah[16][68];
    __shared__ __align__(16) float Bt[6][16][68];  // ih_r, hh_r, ih_z, hh_z, ih_n, hh_n
    const int tid = threadIdx.x;
    const int r0 = blockIdx.x * 64, c0 = blockIdx.y * 64;
    const int lr = tid >> 2;
    const int lk = (tid & 3) << 2;
    const int ty = tid >> 4, tx = tid & 15;
    float accr[4][4], accz[4][4], accni[4][4], accnh[4][4];
#pragma unroll
    for (int i = 0; i < 4; ++i)
#pragma unroll
        for (int j = 0; j < 4; ++j) {
            accr[i][j] = 0.f; accz[i][j] = 0.f;
            accni[i][j] = 0.f; accnh[i][j] = 0.f;
        }

    for (int kc = 0; kc < 256; kc += 16) {
        __syncthreads();
        {
            const int grow = r0 + lr;
            float4 av = make_float4(0.f, 0.f, 0.f, 0.f);
            float4 hv = make_float4(0.f, 0.f, 0.f, 0.f);
            if (grow < N) {
                av = *(const float4*)&agg[(size_t)grow * 256 + kc + lk];
                hv = *(const float4*)&hold[(size_t)grow * 256 + kc + lk];
            }
            Aa[lk + 0][lr] = av.x; Aa[lk + 1][lr] = av.y;
            Aa[lk + 2][lr] = av.z; Aa[lk + 3][lr] = av.w;
            Ah[lk + 0][lr] = hv.x; Ah[lk + 1][lr] = hv.y;
            Ah[lk + 2][lr] = hv.z; Ah[lk + 3][lr] = hv.w;
#pragma unroll
            for (int g = 0; g < 3; ++g) {
                const size_t wrow = (size_t)(g * 256 + c0 + lr) * 256 + kc + lk;
                const float4 bi = *(const float4*)&Wih[wrow];
                const float4 bh = *(const float4*)&Whh[wrow];
                Bt[2 * g + 0][lk + 0][lr] = bi.x; Bt[2 * g + 0][lk + 1][lr] = bi.y;
                Bt[2 * g + 0][lk + 2][lr] = bi.z; Bt[2 * g + 0][lk + 3][lr] = bi.w;
                Bt[2 * g + 1][lk + 0][lr] = bh.x; Bt[2 * g + 1][lk + 1][lr] = bh.y;
                Bt[2 * g + 1][lk + 2][lr] = bh.z; Bt[2 * g + 1][lk + 3][lr] = bh.w;
            }
        }
        __syncthreads();
#pragma unroll
        for (int kk = 0; kk < 16; ++kk) {
            const float4 aa = *(const float4*)&Aa[kk][ty << 2];
            const float4 ah = *(const float4*)&Ah[kk][ty << 2];
            const float4 v0 = *(const float4*)&Bt[0][kk][tx << 2];
            const float4 v1 = *(const float4*)&Bt[1][kk][tx << 2];
            const float4 v2 = *(const float4*)&Bt[2][kk][tx << 2];
            const float4 v3 = *(const float4*)&Bt[3][kk][tx << 2];
            const float4 v4 = *(const float4*)&Bt[4][kk][tx << 2];
            const float4 v5 = *(const float4*)&Bt[5][kk][tx << 2];
            const float ar[4] = {aa.x, aa.y, aa.z, aa.w};
            const float hr[4] = {ah.x, ah.y, ah.z, ah.w};
            const float bri[4] = {v0.x, v0.y, v0.z, v0.w};
            const float brh[4] = {v1.x, v1.y, v1.z, v1.w};
            const float bzi[4] = {v2.x, v2.y, v2.z, v2.w};
            const float bzh[4] = {v3.x, v3.y, v3.z, v3.w};
            const float bnii[4] = {v4.x, v4.y, v4.z, v4.w};
            const float bnhh[4] = {v5.x, v5.y, v5.z, v5.w};
#pragma unroll
            for (int i = 0; i < 4; ++i)
#pragma unroll
                for (int j = 0; j < 4; ++j) {
                    accr[i][j] = fmaf(ar[i], bri[j], accr[i][j]);
                    accr[i][j] = fmaf(hr[i], brh[j], accr[i][j]);
                    accz[i][j] = fmaf(ar[i], bzi[j], accz[i][j]);
                    accz[i][j] = fmaf(hr[i], bzh[j], accz[i][j]);
                    accni[i][j] = fmaf(ar[i], bnii[j], accni[i][j]);
                    accnh[i][j] = fmaf(hr[i], bnhh[j], accnh[i][j]);
                }
        }
    }
    const int cbase = c0 + (tx << 2);
    const float4 brv = *(const float4*)&bsum[cbase];
    const float4 bzv = *(const float4*)&bsum[256 + cbase];
    const float4 biv = *(const float4*)&bni[cbase];
    const float4 bhv = *(const float4*)&bnh[cbase];
    const float rb[4] = {brv.x, brv.y, brv.z, brv.w};
    const float zb[4] = {bzv.x, bzv.y, bzv.z, bzv.w};
    const float ib[4] = {biv.x, biv.y, biv.z, biv.w};
    const float hb[4] = {bhv.x, bhv.y, bhv.z, bhv.w};
#pragma unroll
    for (int i = 0; i < 4; ++i) {
        const int row = r0 + (ty << 2) + i;
        if (row < N) {
            const float4 hv = *(const float4*)&hold[(size_t)row * 256 + cbase];
            const float ho[4] = {hv.x, hv.y, hv.z, hv.w};
            float out[4];
#pragma unroll
            for (int j = 0; j < 4; ++j) {
                const float r = 1.f / (1.f + expf(-(accr[i][j] + rb[j])));
                const float z = 1.f / (1.f + expf(-(accz[i][j] + zb[j])));
                const float nn = tanhf(accni[i][j] + ib[j] + r * (accnh[i][j] + hb[j]));
                out[j] = (1.f - z) * nn + z * ho[j];
            }
            float4 v; v.x = out[0]; v.y = out[1]; v.z = out[2]; v.w = out[3];
            *(float4*)&hnew[(size_t)row * 256 + cbase] = v;
        }
    }
}

// out[n] = sum_t relu(h[n,t]) * fc_w[t] + fc_b ; one 256-thread block per node
__global__ void final_k(const float* __restrict__ h, const void* fcw, const void* fcb,
                        void* out, const int* flags, int N) {
    const int n = blockIdx.x;
    const int t = threadIdx.x;
    const int isbf = flags[0];
    float v = fmaxf(h[(size_t)n * HDIM + t], 0.f) * ldf(fcw, t, isbf);
#pragma unroll
    for (int off = 32; off >= 1; off >>= 1) v += __shfl_down(v, off);
    __shared__ float red[4];
    if ((t & 63) == 0) red[t >> 6] = v;
    __syncthreads();
    if (t == 0) {
        const float s = red[0] + red[1] + red[2] + red[3] + ldf(fcb, 0, isbf);
        if (isbf) ((__hip_bfloat16*)out)[n] = __float2bfloat16(s);
        else      ((float*)out)[n] = s;
    }
}

extern "C" void kernel_launch(void* const* d_in, const int* in_sizes, int n_in,
                              void* d_out, int out_size, void* d_ws, size_t ws_size,
                              hipStream_t stream) {
    const int H = HDIM;
    const int N = in_sizes[0] / H;       // 50000
    const int E = in_sizes[2];           // 800000
    const int L = in_sizes[3] / (H * H); // 5
    const size_t NH = (size_t)N * H;

    float* ws    = (float*)d_ws;
    int*   flags = (int*)ws;                 // 16 floats reserved
    float* buf0  = ws + 16;                  // [N,256]
    float* buf1  = buf0 + NH;                // [N,256]
    float* agg   = buf1 + NH;                // [N,256]
    float* Wt    = agg + NH;                 // [L,256,256]
    float* Wih   = Wt + (size_t)L * H * H;   // [768,256]
    float* Whh   = Wih + 196608;             // [768,256]
    float* bsum  = Whh + 196608;             // [512]
    float* bni   = bsum + 512;               // [256]
    float* bnh   = bni + 256;                // [256]
    // total ~= 39.1M floats ~= 150 MiB

    detect_k<<<dim3(1), dim3(64), 0, stream>>>(d_in[0], d_in[1], flags);
    convert_x_k<<<dim3((unsigned)((NH + 255) / 256)), dim3(256), 0, stream>>>(
        d_in[0], buf0, flags, NH);
    prep_k<<<dim3((L * 65536 + 255) / 256), dim3(256), 0, stream>>>(
        d_in[3], d_in[4], d_in[5], d_in[6], d_in[7],
        Wt, Wih, Whh, bsum, bni, bnh, flags, L);

    const dim3 blk(256);
    const int gm = (N + 63) / 64;
    float* hcur = buf0;
    float* mbuf = buf1;
    for (int l = 0; l < L; ++l) {
        gemm1_k<<<dim3(gm, 4), blk, 0, stream>>>(hcur, Wt + (size_t)l * H * H, mbuf, N);
        zero_k<<<dim3((unsigned)((NH / 4 + 255) / 256)), blk, 0, stream>>>(
            (float4*)agg, NH / 4);
        scatter_k<<<dim3((E + 3) / 4), blk, 0, stream>>>(mbuf, d_in[1], d_in[2], agg, flags, E);
        gates_gru_k<<<dim3(gm, 4), blk, 0, stream>>>(
            agg, hcur, Wih, Whh, bsum, bni, bnh, mbuf, N);
        float* t = hcur; hcur = mbuf; mbuf = t;
    }
    final_k<<<dim3(N), blk, 0, stream>>>(hcur, d_in[8], d_in[9], d_out, flags, N);
}

// Round 3
// 4693.447 us; speedup vs baseline: 3.6390x; 3.6390x over previous
//
#include <hip/hip_runtime.h>
#include <hip/hip_bf16.h>
#include <math.h>

// GGNN: L=5 layers of { m = h@W_l ; agg = scatter_add(ew * m[src] -> dst) ;
//                       h = GRUCell(agg, h) } then out = relu(h)@fc_w^T + fc_b
// H=256, N=50000, E=800000.
//
// R2 lesson: per-edge f32 atomics were 78% of runtime (205M atomics/layer,
// VALUBusy 1%, atomic-throughput bound). Replaced by a device-built CSR
// (by dst, built once per call, ~100us) + a gather-style SpMM: one wave per
// node, register accumulation, zero float atomics. m (51MB) is LLC-resident
// so the gather runs at Infinity-Cache bandwidth.
//
// Float inputs may be bf16 (harness-converted) or f32; edge_index may be
// int32 or int64. Detected on-device (graph-safe, identical work per call).

#define HDIM 256

__device__ __forceinline__ float ldf(const void* p, size_t i, int isbf) {
    if (isbf) return __bfloat162float(((const __hip_bfloat16*)p)[i]);
    return ((const float*)p)[i];
}

// flags[0] = 1 if float tensors are bf16, 0 if f32
// flags[1] = 1 if edge_index is int64, 0 if int32
__global__ void detect_k(const void* x, const void* ei, int* flags) {
    if (blockIdx.x == 0 && threadIdx.x == 0) {
        const __hip_bfloat16* xb = (const __hip_bfloat16*)x;
        int isbf = 1;
        for (int i = 0; i < 1024; ++i) {
            float v = fabsf(__bfloat162float(xb[i]));
            if (!(v < 1e6f)) { isbf = 0; break; }  // f32 read as bf16 -> huge/NaN
        }
        flags[0] = isbf;
        const int* e32 = (const int*)ei;
        int orv = e32[1] | e32[3] | e32[5] | e32[7] | e32[9] | e32[11];
        flags[1] = (orv == 0) ? 1 : 0;  // int64: high words all zero
    }
}

__global__ void convert_x_k(const void* x, float* h, const int* flags, size_t n) {
    size_t i = (size_t)blockIdx.x * blockDim.x + threadIdx.x;
    if (i < n) h[i] = ldf(x, i, flags[0]);
}

// Wt[l][j][k] = weight[l][k][j] (so the layer GEMM is NT form).
// Wih/Whh: [768][256] f32 copies of w_ih/w_hh (gate order r,z,n).
// bsum[512] = b_ih+b_hh for r,z; bni[256] = b_ih_n; bnh[256] = b_hh_n.
__global__ void prep_k(const void* w, const void* wih, const void* whh,
                       const void* bih, const void* bhh,
                       float* Wt, float* Wih, float* Whh,
                       float* bsum, float* bni, float* bnh,
                       const int* flags, int L) {
    int i = blockIdx.x * blockDim.x + threadIdx.x;
    int isbf = flags[0];
    if (i < L * 65536) {
        int l = i >> 16, rem = i & 65535;
        int j = rem >> 8, k = rem & 255;
        Wt[i] = ldf(w, ((size_t)l << 16) + (size_t)k * 256 + j, isbf);
    }
    if (i < 196608) {
        Wih[i] = ldf(wih, i, isbf);
        Whh[i] = ldf(whh, i, isbf);
    }
    if (i < 512) bsum[i] = ldf(bih, i, isbf) + ldf(bhh, i, isbf);
    if (i < 256) {
        bni[i] = ldf(bih, 512 + i, isbf);
        bnh[i] = ldf(bhh, 512 + i, isbf);
    }
}

// ---------------- CSR build (by dst), once per call ----------------

__global__ void zero_int_k(int* p, int n) {
    int i = blockIdx.x * blockDim.x + threadIdx.x;
    if (i < n) p[i] = 0;
}

__global__ void count_k(const void* ei, int* cnt, const int* flags, int E) {
    int e = blockIdx.x * blockDim.x + threadIdx.x;
    if (e >= E) return;
    const int* e32 = (const int*)ei;
    int d = flags[1] ? e32[2 * ((size_t)E + e)] : e32[(size_t)E + e];
    atomicAdd(&cnt[d], 1);
}

// Block-wise inclusive scan (Hillis-Steele over 256), write exclusive-within-
// block to ptr, block total to bsumN[blockIdx.x].
__global__ __launch_bounds__(256)
void scan1_k(const int* cnt, int* ptr, int* bsumN, int N) {
    __shared__ int s[256];
    const int t = threadIdx.x;
    const int gid = blockIdx.x * 256 + t;
    int v = (gid < N) ? cnt[gid] : 0;
    const int own = v;
    s[t] = v;
    __syncthreads();
#pragma unroll
    for (int off = 1; off < 256; off <<= 1) {
        int add = (t >= off) ? s[t - off] : 0;
        __syncthreads();
        s[t] += add;
        __syncthreads();
    }
    if (gid < N) ptr[gid] = s[t] - own;
    if (t == 255) bsumN[blockIdx.x] = s[255];
}

// Single block: exclusive scan of NB block totals (sequential chunks of 256
// with running carry; handles any NB).
__global__ __launch_bounds__(256)
void scan2_k(int* bsumN, int NB) {
    __shared__ int s[256];
    __shared__ int carry;
    const int t = threadIdx.x;
    if (t == 0) carry = 0;
    __syncthreads();
    for (int base = 0; base < NB; base += 256) {
        const int i = base + t;
        int v = (i < NB) ? bsumN[i] : 0;
        const int own = v;
        s[t] = v;
        __syncthreads();
#pragma unroll
        for (int off = 1; off < 256; off <<= 1) {
            int add = (t >= off) ? s[t - off] : 0;
            __syncthreads();
            s[t] += add;
            __syncthreads();
        }
        if (i < NB) bsumN[i] = carry + s[t] - own;
        __syncthreads();
        if (t == 0) carry += s[255];
        __syncthreads();
    }
}

// Add block offsets; init per-node cursor; set ptr[N]=E.
__global__ void scan3_k(int* ptr, int* cursor, const int* bsumN, int N, int E) {
    const int gid = blockIdx.x * 256 + threadIdx.x;
    if (gid < N) {
        const int p = ptr[gid] + bsumN[blockIdx.x];
        ptr[gid] = p;
        cursor[gid] = p;
    }
    if (gid == 0) ptr[N] = E;
}

__global__ void fill_k(const void* ei, const void* ew, int* cursor,
                       int* srcs, float* wse, const int* flags, int E) {
    int e = blockIdx.x * blockDim.x + threadIdx.x;
    if (e >= E) return;
    const int* e32 = (const int*)ei;
    int s, d;
    if (flags[1]) { s = e32[2 * (size_t)e]; d = e32[2 * ((size_t)E + e)]; }
    else          { s = e32[e];             d = e32[(size_t)E + e]; }
    const int p = atomicAdd(&cursor[d], 1);
    srcs[p] = s;
    wse[p] = ldf(ew, e, flags[0]);
}

// ---------------- SpMM gather: agg[d] = sum_j w_j * m[src_j] ----------------
// One 64-lane wave per dst node; float4 per lane; register accumulate;
// single coalesced store. No atomics.
__global__ __launch_bounds__(256)
void spmm_k(const float* __restrict__ m, const int* __restrict__ ptr,
            const int* __restrict__ srcs, const float* __restrict__ wse,
            float* __restrict__ agg, int N) {
    const int node = blockIdx.x * 4 + (threadIdx.x >> 6);
    if (node >= N) return;
    const int lane4 = (threadIdx.x & 63) << 2;
    const int p0 = ptr[node], p1 = ptr[node + 1];
    float4 acc = make_float4(0.f, 0.f, 0.f, 0.f);
    int j = p0;
    for (; j + 1 < p1; j += 2) {
        const int s0 = srcs[j], s1 = srcs[j + 1];
        const float w0 = wse[j], w1 = wse[j + 1];
        const float4 v0 = *(const float4*)&m[(size_t)s0 * HDIM + lane4];
        const float4 v1 = *(const float4*)&m[(size_t)s1 * HDIM + lane4];
        acc.x = fmaf(w0, v0.x, acc.x); acc.y = fmaf(w0, v0.y, acc.y);
        acc.z = fmaf(w0, v0.z, acc.z); acc.w = fmaf(w0, v0.w, acc.w);
        acc.x = fmaf(w1, v1.x, acc.x); acc.y = fmaf(w1, v1.y, acc.y);
        acc.z = fmaf(w1, v1.z, acc.z); acc.w = fmaf(w1, v1.w, acc.w);
    }
    if (j < p1) {
        const int s0 = srcs[j];
        const float w0 = wse[j];
        const float4 v0 = *(const float4*)&m[(size_t)s0 * HDIM + lane4];
        acc.x = fmaf(w0, v0.x, acc.x); acc.y = fmaf(w0, v0.y, acc.y);
        acc.z = fmaf(w0, v0.z, acc.z); acc.w = fmaf(w0, v0.w, acc.w);
    }
    *(float4*)&agg[(size_t)node * HDIM + lane4] = acc;
}

// ---------------- dense kernels (unchanged from R2) ----------------

// C[M,256] = A[M,256] @ B[256,256]^T. 64x64 tile / 256-thread block, BK=16,
// k-major LDS, 4x4 acc per thread.
__global__ __launch_bounds__(256)
void gemm1_k(const float* __restrict__ A, const float* __restrict__ B,
             float* __restrict__ C, int M) {
    __shared__ __align__(16) float As[16][68];
    __shared__ __align__(16) float Bs[16][68];
    const int tid = threadIdx.x;
    const int row0 = blockIdx.x * 64, col0 = blockIdx.y * 64;
    const int lr = tid >> 2;
    const int lk = (tid & 3) << 2;
    const int ty = tid >> 4, tx = tid & 15;
    float acc[4][4];
#pragma unroll
    for (int i = 0; i < 4; ++i)
#pragma unroll
        for (int j = 0; j < 4; ++j) acc[i][j] = 0.f;

    for (int kc = 0; kc < 256; kc += 16) {
        __syncthreads();
        {
            const int grow = row0 + lr;
            float4 av = make_float4(0.f, 0.f, 0.f, 0.f);
            if (grow < M) av = *(const float4*)&A[(size_t)grow * 256 + kc + lk];
            const float4 bv = *(const float4*)&B[(size_t)(col0 + lr) * 256 + kc + lk];
            As[lk + 0][lr] = av.x; As[lk + 1][lr] = av.y;
            As[lk + 2][lr] = av.z; As[lk + 3][lr] = av.w;
            Bs[lk + 0][lr] = bv.x; Bs[lk + 1][lr] = bv.y;
            Bs[lk + 2][lr] = bv.z; Bs[lk + 3][lr] = bv.w;
        }
        __syncthreads();
#pragma unroll
        for (int kk = 0; kk < 16; ++kk) {
            const float4 a = *(const float4*)&As[kk][ty << 2];
            const float4 b = *(const float4*)&Bs[kk][tx << 2];
            const float ar[4] = {a.x, a.y, a.z, a.w};
            const float br[4] = {b.x, b.y, b.z, b.w};
#pragma unroll
            for (int i = 0; i < 4; ++i)
#pragma unroll
                for (int j = 0; j < 4; ++j) acc[i][j] = fmaf(ar[i], br[j], acc[i][j]);
        }
    }
#pragma unroll
    for (int i = 0; i < 4; ++i) {
        const int row = row0 + (ty << 2) + i;
        if (row < M) {
            float4 v;
            v.x = acc[i][0]; v.y = acc[i][1]; v.z = acc[i][2]; v.w = acc[i][3];
            *(float4*)&C[(size_t)row * 256 + col0 + (tx << 2)] = v;
        }
    }
}

// Fused GRU gate GEMMs + pointwise update (no [N,1024] buffer).
__global__ __launch_bounds__(256)
void gates_gru_k(const float* __restrict__ agg, const float* __restrict__ hold,
                 const float* __restrict__ Wih, const float* __restrict__ Whh,
                 const float* __restrict__ bsum, const float* __restrict__ bni,
                 const float* __restrict__ bnh,
                 float* __restrict__ hnew, int N) {
    __shared__ __align__(16) float Aa[16][68];
    __shared__ __align__(16) float Ah[16][68];
    __shared__ __align__(16) float Bt[6][16][68];  // ih_r, hh_r, ih_z, hh_z, ih_n, hh_n
    const int tid = threadIdx.x;
    const int r0 = blockIdx.x * 64, c0 = blockIdx.y * 64;
    const int lr = tid >> 2;
    const int lk = (tid & 3) << 2;
    const int ty = tid >> 4, tx = tid & 15;
    float accr[4][4], accz[4][4], accni[4][4], accnh[4][4];
#pragma unroll
    for (int i = 0; i < 4; ++i)
#pragma unroll
        for (int j = 0; j < 4; ++j) {
            accr[i][j] = 0.f; accz[i][j] = 0.f;
            accni[i][j] = 0.f; accnh[i][j] = 0.f;
        }

    for (int kc = 0; kc < 256; kc += 16) {
        __syncthreads();
        {
            const int grow = r0 + lr;
            float4 av = make_float4(0.f, 0.f, 0.f, 0.f);
            float4 hv = make_float4(0.f, 0.f, 0.f, 0.f);
            if (grow < N) {
                av = *(const float4*)&agg[(size_t)grow * 256 + kc + lk];
                hv = *(const float4*)&hold[(size_t)grow * 256 + kc + lk];
            }
            Aa[lk + 0][lr] = av.x; Aa[lk + 1][lr] = av.y;
            Aa[lk + 2][lr] = av.z; Aa[lk + 3][lr] = av.w;
            Ah[lk + 0][lr] = hv.x; Ah[lk + 1][lr] = hv.y;
            Ah[lk + 2][lr] = hv.z; Ah[lk + 3][lr] = hv.w;
#pragma unroll
            for (int g = 0; g < 3; ++g) {
                const size_t wrow = (size_t)(g * 256 + c0 + lr) * 256 + kc + lk;
                const float4 bi = *(const float4*)&Wih[wrow];
                const float4 bh = *(const float4*)&Whh[wrow];
                Bt[2 * g + 0][lk + 0][lr] = bi.x; Bt[2 * g + 0][lk + 1][lr] = bi.y;
                Bt[2 * g + 0][lk + 2][lr] = bi.z; Bt[2 * g + 0][lk + 3][lr] = bi.w;
                Bt[2 * g + 1][lk + 0][lr] = bh.x; Bt[2 * g + 1][lk + 1][lr] = bh.y;
                Bt[2 * g + 1][lk + 2][lr] = bh.z; Bt[2 * g + 1][lk + 3][lr] = bh.w;
            }
        }
        __syncthreads();
#pragma unroll
        for (int kk = 0; kk < 16; ++kk) {
            const float4 aa = *(const float4*)&Aa[kk][ty << 2];
            const float4 ah = *(const float4*)&Ah[kk][ty << 2];
            const float4 v0 = *(const float4*)&Bt[0][kk][tx << 2];
            const float4 v1 = *(const float4*)&Bt[1][kk][tx << 2];
            const float4 v2 = *(const float4*)&Bt[2][kk][tx << 2];
            const float4 v3 = *(const float4*)&Bt[3][kk][tx << 2];
            const float4 v4 = *(const float4*)&Bt[4][kk][tx << 2];
            const float4 v5 = *(const float4*)&Bt[5][kk][tx << 2];
            const float ar[4] = {aa.x, aa.y, aa.z, aa.w};
            const float hr[4] = {ah.x, ah.y, ah.z, ah.w};
            const float bri[4] = {v0.x, v0.y, v0.z, v0.w};
            const float brh[4] = {v1.x, v1.y, v1.z, v1.w};
            const float bzi[4] = {v2.x, v2.y, v2.z, v2.w};
            const float bzh[4] = {v3.x, v3.y, v3.z, v3.w};
            const float bnii[4] = {v4.x, v4.y, v4.z, v4.w};
            const float bnhh[4] = {v5.x, v5.y, v5.z, v5.w};
#pragma unroll
            for (int i = 0; i < 4; ++i)
#pragma unroll
                for (int j = 0; j < 4; ++j) {
                    accr[i][j] = fmaf(ar[i], bri[j], accr[i][j]);
                    accr[i][j] = fmaf(hr[i], brh[j], accr[i][j]);
                    accz[i][j] = fmaf(ar[i], bzi[j], accz[i][j]);
                    accz[i][j] = fmaf(hr[i], bzh[j], accz[i][j]);
                    accni[i][j] = fmaf(ar[i], bnii[j], accni[i][j]);
                    accnh[i][j] = fmaf(hr[i], bnhh[j], accnh[i][j]);
                }
        }
    }
    const int cbase = c0 + (tx << 2);
    const float4 brv = *(const float4*)&bsum[cbase];
    const float4 bzv = *(const float4*)&bsum[256 + cbase];
    const float4 biv = *(const float4*)&bni[cbase];
    const float4 bhv = *(const float4*)&bnh[cbase];
    const float rb[4] = {brv.x, brv.y, brv.z, brv.w};
    const float zb[4] = {bzv.x, bzv.y, bzv.z, bzv.w};
    const float ib[4] = {biv.x, biv.y, biv.z, biv.w};
    const float hb[4] = {bhv.x, bhv.y, bhv.z, bhv.w};
#pragma unroll
    for (int i = 0; i < 4; ++i) {
        const int row = r0 + (ty << 2) + i;
        if (row < N) {
            const float4 hv = *(const float4*)&hold[(size_t)row * 256 + cbase];
            const float ho[4] = {hv.x, hv.y, hv.z, hv.w};
            float out[4];
#pragma unroll
            for (int j = 0; j < 4; ++j) {
                const float r = 1.f / (1.f + expf(-(accr[i][j] + rb[j])));
                const float z = 1.f / (1.f + expf(-(accz[i][j] + zb[j])));
                const float nn = tanhf(accni[i][j] + ib[j] + r * (accnh[i][j] + hb[j]));
                out[j] = (1.f - z) * nn + z * ho[j];
            }
            float4 v; v.x = out[0]; v.y = out[1]; v.z = out[2]; v.w = out[3];
            *(float4*)&hnew[(size_t)row * 256 + cbase] = v;
        }
    }
}

// out[n] = sum_t relu(h[n,t]) * fc_w[t] + fc_b ; one 256-thread block per node
__global__ void final_k(const float* __restrict__ h, const void* fcw, const void* fcb,
                        void* out, const int* flags, int N) {
    const int n = blockIdx.x;
    const int t = threadIdx.x;
    const int isbf = flags[0];
    float v = fmaxf(h[(size_t)n * HDIM + t], 0.f) * ldf(fcw, t, isbf);
#pragma unroll
    for (int off = 32; off >= 1; off >>= 1) v += __shfl_down(v, off);
    __shared__ float red[4];
    if ((t & 63) == 0) red[t >> 6] = v;
    __syncthreads();
    if (t == 0) {
        const float s = red[0] + red[1] + red[2] + red[3] + ldf(fcb, 0, isbf);
        if (isbf) ((__hip_bfloat16*)out)[n] = __float2bfloat16(s);
        else      ((float*)out)[n] = s;
    }
}

extern "C" void kernel_launch(void* const* d_in, const int* in_sizes, int n_in,
                              void* d_out, int out_size, void* d_ws, size_t ws_size,
                              hipStream_t stream) {
    const int H = HDIM;
    const int N = in_sizes[0] / H;       // 50000
    const int E = in_sizes[2];           // 800000
    const int L = in_sizes[3] / (H * H); // 5
    const size_t NH = (size_t)N * H;
    const int NB = (N + 255) / 256;

    float* ws    = (float*)d_ws;
    int*   flags = (int*)ws;                 // 16 floats reserved
    float* buf0  = ws + 16;                  // [N,256]
    float* buf1  = buf0 + NH;                // [N,256]
    float* agg   = buf1 + NH;                // [N,256]
    float* Wt    = agg + NH;                 // [L,256,256]
    float* Wih   = Wt + (size_t)L * H * H;   // [768,256]
    float* Whh   = Wih + 196608;             // [768,256]
    float* bsum  = Whh + 196608;             // [512]
    float* bni   = bsum + 512;               // [256]
    float* bnh   = bni + 256;                // [256]
    int*   ptr    = (int*)(bnh + 256);       // [N+1]
    int*   cursor = ptr + (N + 1);           // [N]
    int*   bsumN  = cursor + N;              // [NB]
    int*   srcs   = bsumN + NB;              // [E]
    float* wse    = (float*)(srcs + E);      // [E]
    // total ~= 41M f32-equiv ~= 165 MiB

    detect_k<<<dim3(1), dim3(64), 0, stream>>>(d_in[0], d_in[1], flags);
    convert_x_k<<<dim3((unsigned)((NH + 255) / 256)), dim3(256), 0, stream>>>(
        d_in[0], buf0, flags, NH);
    prep_k<<<dim3((L * 65536 + 255) / 256), dim3(256), 0, stream>>>(
        d_in[3], d_in[4], d_in[5], d_in[6], d_in[7],
        Wt, Wih, Whh, bsum, bni, bnh, flags, L);

    // CSR build (reuses `cursor` as the count buffer; scan writes ptr)
    zero_int_k<<<dim3(NB), dim3(256), 0, stream>>>(cursor, N);
    count_k<<<dim3((E + 255) / 256), dim3(256), 0, stream>>>(d_in[1], cursor, flags, E);
    scan1_k<<<dim3(NB), dim3(256), 0, stream>>>(cursor, ptr, bsumN, N);
    scan2_k<<<dim3(1), dim3(256), 0, stream>>>(bsumN, NB);
    scan3_k<<<dim3(NB), dim3(256), 0, stream>>>(ptr, cursor, bsumN, N, E);
    fill_k<<<dim3((E + 255) / 256), dim3(256), 0, stream>>>(
        d_in[1], d_in[2], cursor, srcs, wse, flags, E);

    const dim3 blk(256);
    const int gm = (N + 63) / 64;
    float* hcur = buf0;
    float* mbuf = buf1;
    for (int l = 0; l < L; ++l) {
        gemm1_k<<<dim3(gm, 4), blk, 0, stream>>>(hcur, Wt + (size_t)l * H * H, mbuf, N);
        spmm_k<<<dim3((N + 3) / 4), blk, 0, stream>>>(mbuf, ptr, srcs, wse, agg, N);
        gates_gru_k<<<dim3(gm, 4), blk, 0, stream>>>(
            agg, hcur, Wih, Whh, bsum, bni, bnh, mbuf, N);
        float* t = hcur; hcur = mbuf; mbuf = t;
    }
    final_k<<<dim3(N), blk, 0, stream>>>(hcur, d_in[8], d_in[9], d_out, flags, N);
}

// Round 4
// 4610.119 us; speedup vs baseline: 3.7048x; 1.0181x over previous
//
#include <hip/hip_runtime.h>
#include <hip/hip_bf16.h>
#include <math.h>

// GGNN: L=5 layers of { m = h@W_l ; agg = scatter_add(ew * m[src] -> dst) ;
//                       h = GRUCell(agg, h) } then out = relu(h)@fc_w^T + fc_b
// H=256, N=50000, E=800000.
//
// R3 lesson: f32 FMA gates kernel was register-starved (96 acc > 92 VGPR ->
// AGPR shuttling, 36% of f32 peak). R4: split-bf16 MFMA. h/agg stored as
// hi/lo bf16 plane pairs; each GEMM = A_hi@B + A_lo@B (+ A_hi@B_lo when
// inputs are f32; weights are exact bf16 when harness converted them).
// MFMA A-frags ([row,k] row-major) and B-frags (NT [col,k]) are contiguous
// 16B loads -> no LDS, no barriers. Error ~2^-17 relative == f32-quality.
//
// Workspace ~165MB (R3-proven safe): two NH*4-byte regions (h planes / m f32,
// rotated; h_new aliases dead m), agg planes, weight planes, CSR.

#define HDIM 256

using bf16x8 = __attribute__((ext_vector_type(8))) short;
using f32x4  = __attribute__((ext_vector_type(4))) float;

__device__ __forceinline__ bf16x8 ldfrag(const ushort* p) {
    union { uint4 u; bf16x8 f; } x;
    x.u = *(const uint4*)p;
    return x.f;
}
#define MFMA(a, b, c) __builtin_amdgcn_mfma_f32_16x16x32_bf16((a), (b), (c), 0, 0, 0)

__device__ __forceinline__ float ldf(const void* p, size_t i, int isbf) {
    if (isbf) return __bfloat162float(((const __hip_bfloat16*)p)[i]);
    return ((const float*)p)[i];
}
__device__ __forceinline__ ushort f2bs(float v) {
    __hip_bfloat16 b = __float2bfloat16(v);
    return *(ushort*)&b;
}
__device__ __forceinline__ float bs2f(ushort u) {
    __hip_bfloat16 b = *(__hip_bfloat16*)&u;
    return __bfloat162float(b);
}

// flags[0] = 1 if float tensors are bf16, 0 if f32
// flags[1] = 1 if edge_index is int64, 0 if int32
__global__ void detect_k(const void* x, const void* ei, int* flags) {
    if (blockIdx.x == 0 && threadIdx.x == 0) {
        const __hip_bfloat16* xb = (const __hip_bfloat16*)x;
        int isbf = 1;
        for (int i = 0; i < 1024; ++i) {
            float v = fabsf(__bfloat162float(xb[i]));
            if (!(v < 1e6f)) { isbf = 0; break; }
        }
        flags[0] = isbf;
        const int* e32 = (const int*)ei;
        int orv = e32[1] | e32[3] | e32[5] | e32[7] | e32[9] | e32[11];
        flags[1] = (orv == 0) ? 1 : 0;
    }
}

// x -> h hi/lo planes
__global__ void conv_h0_k(const void* x, ushort* hH, ushort* hL,
                          const int* flags, size_t n) {
    size_t i = (size_t)blockIdx.x * blockDim.x + threadIdx.x;
    if (i >= n) return;
    const float v = ldf(x, i, flags[0]);
    const ushort h = f2bs(v);
    hH[i] = h;
    hL[i] = f2bs(v - bs2f(h));
}

// Weight planes. Wt[l][j][k] = weight[l][k][j] (NT form). Wih/Whh direct
// [768][256] copies (gate order r,z,n). All split hi/lo (lo==0 when bf16
// input, naturally). Biases f32: bsum=b_ih+b_hh (r,z); bni/bnh = n biases.
__global__ void prep_k(const void* w, const void* wih, const void* whh,
                       const void* bih, const void* bhh,
                       ushort* WtH, ushort* WtL, ushort* WihH, ushort* WihL,
                       ushort* WhhH, ushort* WhhL,
                       float* bsum, float* bni, float* bnh,
                       const int* flags, int L) {
    int i = blockIdx.x * blockDim.x + threadIdx.x;
    int isbf = flags[0];
    if (i < L * 65536) {
        int l = i >> 16, rem = i & 65535;
        int j = rem >> 8, k = rem & 255;
        float v = ldf(w, ((size_t)l << 16) + (size_t)k * 256 + j, isbf);
        ushort h = f2bs(v);
        WtH[i] = h; WtL[i] = f2bs(v - bs2f(h));
    }
    if (i < 196608) {
        float a = ldf(wih, i, isbf);
        ushort ah = f2bs(a);
        WihH[i] = ah; WihL[i] = f2bs(a - bs2f(ah));
        float b = ldf(whh, i, isbf);
        ushort bh = f2bs(b);
        WhhH[i] = bh; WhhL[i] = f2bs(b - bs2f(bh));
    }
    if (i < 512) bsum[i] = ldf(bih, i, isbf) + ldf(bhh, i, isbf);
    if (i < 256) {
        bni[i] = ldf(bih, 512 + i, isbf);
        bnh[i] = ldf(bhh, 512 + i, isbf);
    }
}

// ---------------- CSR build (by dst), once per call ----------------

__global__ void zero_int_k(int* p, int n) {
    int i = blockIdx.x * blockDim.x + threadIdx.x;
    if (i < n) p[i] = 0;
}

__global__ void count_k(const void* ei, int* cnt, const int* flags, int E) {
    int e = blockIdx.x * blockDim.x + threadIdx.x;
    if (e >= E) return;
    const int* e32 = (const int*)ei;
    int d = flags[1] ? e32[2 * ((size_t)E + e)] : e32[(size_t)E + e];
    atomicAdd(&cnt[d], 1);
}

__global__ __launch_bounds__(256)
void scan1_k(const int* cnt, int* ptr, int* bsumN, int N) {
    __shared__ int s[256];
    const int t = threadIdx.x;
    const int gid = blockIdx.x * 256 + t;
    int v = (gid < N) ? cnt[gid] : 0;
    const int own = v;
    s[t] = v;
    __syncthreads();
#pragma unroll
    for (int off = 1; off < 256; off <<= 1) {
        int add = (t >= off) ? s[t - off] : 0;
        __syncthreads();
        s[t] += add;
        __syncthreads();
    }
    if (gid < N) ptr[gid] = s[t] - own;
    if (t == 255) bsumN[blockIdx.x] = s[255];
}

__global__ __launch_bounds__(256)
void scan2_k(int* bsumN, int NB) {
    __shared__ int s[256];
    __shared__ int carry;
    const int t = threadIdx.x;
    if (t == 0) carry = 0;
    __syncthreads();
    for (int base = 0; base < NB; base += 256) {
        const int i = base + t;
        int v = (i < NB) ? bsumN[i] : 0;
        const int own = v;
        s[t] = v;
        __syncthreads();
#pragma unroll
        for (int off = 1; off < 256; off <<= 1) {
            int add = (t >= off) ? s[t - off] : 0;
            __syncthreads();
            s[t] += add;
            __syncthreads();
        }
        if (i < NB) bsumN[i] = carry + s[t] - own;
        __syncthreads();
        if (t == 0) carry += s[255];
        __syncthreads();
    }
}

__global__ void scan3_k(int* ptr, int* cursor, const int* bsumN, int N, int E) {
    const int gid = blockIdx.x * 256 + threadIdx.x;
    if (gid < N) {
        const int p = ptr[gid] + bsumN[blockIdx.x];
        ptr[gid] = p;
        cursor[gid] = p;
    }
    if (gid == 0) ptr[N] = E;
}

__global__ void fill_k(const void* ei, const void* ew, int* cursor,
                       int* srcs, float* wse, const int* flags, int E) {
    int e = blockIdx.x * blockDim.x + threadIdx.x;
    if (e >= E) return;
    const int* e32 = (const int*)ei;
    int s, d;
    if (flags[1]) { s = e32[2 * (size_t)e]; d = e32[2 * ((size_t)E + e)]; }
    else          { s = e32[e];             d = e32[(size_t)E + e]; }
    const int p = atomicAdd(&cursor[d], 1);
    srcs[p] = s;
    wse[p] = ldf(ew, e, flags[0]);
}

// ---------------- SpMM gather: agg[d] = sum_j w_j * m[src_j] ----------------
// One wave per dst node; f32 accumulate; epilogue splits to hi/lo bf16 planes.
__global__ __launch_bounds__(256)
void spmm_k(const float* __restrict__ m, const int* __restrict__ ptr,
            const int* __restrict__ srcs, const float* __restrict__ wse,
            ushort* __restrict__ aggH, ushort* __restrict__ aggL, int N) {
    const int node = blockIdx.x * 4 + (threadIdx.x >> 6);
    if (node >= N) return;
    const int lane4 = (threadIdx.x & 63) << 2;
    const int p0 = ptr[node], p1 = ptr[node + 1];
    float4 acc = make_float4(0.f, 0.f, 0.f, 0.f);
    int j = p0;
    for (; j + 1 < p1; j += 2) {
        const int s0 = srcs[j], s1 = srcs[j + 1];
        const float w0 = wse[j], w1 = wse[j + 1];
        const float4 v0 = *(const float4*)&m[(size_t)s0 * HDIM + lane4];
        const float4 v1 = *(const float4*)&m[(size_t)s1 * HDIM + lane4];
        acc.x = fmaf(w0, v0.x, acc.x); acc.y = fmaf(w0, v0.y, acc.y);
        acc.z = fmaf(w0, v0.z, acc.z); acc.w = fmaf(w0, v0.w, acc.w);
        acc.x = fmaf(w1, v1.x, acc.x); acc.y = fmaf(w1, v1.y, acc.y);
        acc.z = fmaf(w1, v1.z, acc.z); acc.w = fmaf(w1, v1.w, acc.w);
    }
    if (j < p1) {
        const int s0 = srcs[j];
        const float w0 = wse[j];
        const float4 v0 = *(const float4*)&m[(size_t)s0 * HDIM + lane4];
        acc.x = fmaf(w0, v0.x, acc.x); acc.y = fmaf(w0, v0.y, acc.y);
        acc.z = fmaf(w0, v0.z, acc.z); acc.w = fmaf(w0, v0.w, acc.w);
    }
    ushort4 hi, lo;
    hi.x = f2bs(acc.x); lo.x = f2bs(acc.x - bs2f(hi.x));
    hi.y = f2bs(acc.y); lo.y = f2bs(acc.y - bs2f(hi.y));
    hi.z = f2bs(acc.z); lo.z = f2bs(acc.z - bs2f(hi.z));
    hi.w = f2bs(acc.w); lo.w = f2bs(acc.w - bs2f(hi.w));
    *(ushort4*)&aggH[(size_t)node * HDIM + lane4] = hi;
    *(ushort4*)&aggL[(size_t)node * HDIM + lane4] = lo;
}

// ---------------- MFMA GEMMs (no LDS, no barriers) ----------------
// Wave = 16 rows x 64 cols via 4x mfma_f32_16x16x32_bf16 col-blocks.
// Block = 4 waves = 64 rows. Grid = (ceil(N/64), 4 col-groups of 64).
// A-frag: lane reads plane[(r0w + lane&15)*256 + ks + (lane>>4)*8] (16B).
// B-frag (NT): lane reads W[(col)*256 + ks + (lane>>4)*8] (16B).
// C/D: col = lane&15, row = (lane>>4)*4 + reg  [m89-verified mapping].

// m = h @ Wt^T (one weight matrix)
__global__ __launch_bounds__(256)
void mfma_gemm1_k(const ushort* __restrict__ hH, const ushort* __restrict__ hL,
                  const ushort* __restrict__ WH, const ushort* __restrict__ WL,
                  float* __restrict__ m, const int* __restrict__ flags, int N) {
    const int lane = threadIdx.x & 63;
    const int r0w = blockIdx.x * 64 + (threadIdx.x >> 6) * 16;
    const int c0 = blockIdx.y * 64;
    const int lm = lane & 15, lq = lane >> 4;
    const size_t arow = (size_t)(r0w + lm) * 256;
    const int fullsplit = !flags[0];
    f32x4 acc[4];
#pragma unroll
    for (int cb = 0; cb < 4; ++cb) acc[cb] = (f32x4){0.f, 0.f, 0.f, 0.f};

    for (int ks = 0; ks < 256; ks += 32) {
        const size_t ao = arow + ks + lq * 8;
        const bf16x8 ah = ldfrag(hH + ao);
        const bf16x8 al = ldfrag(hL + ao);
#pragma unroll
        for (int cb = 0; cb < 4; ++cb) {
            const size_t wr = (size_t)(c0 + cb * 16 + lm) * 256 + ks + lq * 8;
            const bf16x8 w = ldfrag(WH + wr);
            acc[cb] = MFMA(ah, w, acc[cb]);
            acc[cb] = MFMA(al, w, acc[cb]);
            if (fullsplit) acc[cb] = MFMA(ah, ldfrag(WL + wr), acc[cb]);
        }
    }
#pragma unroll
    for (int cb = 0; cb < 4; ++cb) {
        const int col = c0 + cb * 16 + lm;
#pragma unroll
        for (int v = 0; v < 4; ++v) {
            const int row = r0w + lq * 4 + v;
            if (row < N) m[(size_t)row * 256 + col] = acc[cb][v];
        }
    }
}

// Fused GRU gates + update: r,z get agg@Wih + hold@Whh (hi+lo products),
// n_i = agg@Wih_n, n_h = hold@Whh_n; epilogue does sigmoid/tanh/mix and
// writes h_new hi/lo planes.
__global__ __launch_bounds__(256)
void mfma_gates_k(const ushort* __restrict__ agH, const ushort* __restrict__ agL,
                  const ushort* __restrict__ hoH, const ushort* __restrict__ hoL,
                  const ushort* __restrict__ WihH, const ushort* __restrict__ WihL,
                  const ushort* __restrict__ WhhH, const ushort* __restrict__ WhhL,
                  const float* __restrict__ bsum, const float* __restrict__ bni,
                  const float* __restrict__ bnh,
                  ushort* __restrict__ hnH, ushort* __restrict__ hnL,
                  const int* __restrict__ flags, int N) {
    const int lane = threadIdx.x & 63;
    const int r0w = blockIdx.x * 64 + (threadIdx.x >> 6) * 16;
    const int c0 = blockIdx.y * 64;
    const int lm = lane & 15, lq = lane >> 4;
    const size_t arow = (size_t)(r0w + lm) * 256;
    const int fullsplit = !flags[0];
    f32x4 aR[4], aZ[4], aNI[4], aNH[4];
#pragma unroll
    for (int cb = 0; cb < 4; ++cb) {
        aR[cb] = (f32x4){0.f, 0.f, 0.f, 0.f};
        aZ[cb] = (f32x4){0.f, 0.f, 0.f, 0.f};
        aNI[cb] = (f32x4){0.f, 0.f, 0.f, 0.f};
        aNH[cb] = (f32x4){0.f, 0.f, 0.f, 0.f};
    }

    for (int ks = 0; ks < 256; ks += 32) {
        const size_t ao = arow + ks + lq * 8;
        const bf16x8 ah = ldfrag(agH + ao);
        const bf16x8 al = ldfrag(agL + ao);
        const bf16x8 hh = ldfrag(hoH + ao);
        const bf16x8 hl = ldfrag(hoL + ao);
#pragma unroll
        for (int cb = 0; cb < 4; ++cb) {
            const size_t wr = (size_t)(c0 + cb * 16 + lm) * 256 + ks + lq * 8;
            const bf16x8 wri = ldfrag(WihH + wr);
            const bf16x8 wrh = ldfrag(WhhH + wr);
            aR[cb] = MFMA(ah, wri, aR[cb]);
            aR[cb] = MFMA(al, wri, aR[cb]);
            aR[cb] = MFMA(hh, wrh, aR[cb]);
            aR[cb] = MFMA(hl, wrh, aR[cb]);
            const bf16x8 wzi = ldfrag(WihH + wr + 65536);
            const bf16x8 wzh = ldfrag(WhhH + wr + 65536);
            aZ[cb] = MFMA(ah, wzi, aZ[cb]);
            aZ[cb] = MFMA(al, wzi, aZ[cb]);
            aZ[cb] = MFMA(hh, wzh, aZ[cb]);
            aZ[cb] = MFMA(hl, wzh, aZ[cb]);
            const bf16x8 wni = ldfrag(WihH + wr + 131072);
            const bf16x8 wnh = ldfrag(WhhH + wr + 131072);
            aNI[cb] = MFMA(ah, wni, aNI[cb]);
            aNI[cb] = MFMA(al, wni, aNI[cb]);
            aNH[cb] = MFMA(hh, wnh, aNH[cb]);
            aNH[cb] = MFMA(hl, wnh, aNH[cb]);
            if (fullsplit) {
                aR[cb] = MFMA(ah, ldfrag(WihL + wr), aR[cb]);
                aR[cb] = MFMA(hh, ldfrag(WhhL + wr), aR[cb]);
                aZ[cb] = MFMA(ah, ldfrag(WihL + wr + 65536), aZ[cb]);
                aZ[cb] = MFMA(hh, ldfrag(WhhL + wr + 65536), aZ[cb]);
                aNI[cb] = MFMA(ah, ldfrag(WihL + wr + 131072), aNI[cb]);
                aNH[cb] = MFMA(hh, ldfrag(WhhL + wr + 131072), aNH[cb]);
            }
        }
    }
#pragma unroll
    for (int cb = 0; cb < 4; ++cb) {
        const int col = c0 + cb * 16 + lm;
        const float rb = bsum[col];
        const float zb = bsum[256 + col];
        const float ib = bni[col];
        const float hb = bnh[col];
#pragma unroll
        for (int v = 0; v < 4; ++v) {
            const int row = r0w + lq * 4 + v;
            if (row < N) {
                const size_t off = (size_t)row * 256 + col;
                const float hold = bs2f(hoH[off]) + bs2f(hoL[off]);
                const float r = 1.f / (1.f + expf(-(aR[cb][v] + rb)));
                const float z = 1.f / (1.f + expf(-(aZ[cb][v] + zb)));
                const float nn = tanhf(aNI[cb][v] + ib + r * (aNH[cb][v] + hb));
                const float hv = (1.f - z) * nn + z * hold;
                const ushort hi = f2bs(hv);
                hnH[off] = hi;
                hnL[off] = f2bs(hv - bs2f(hi));
            }
        }
    }
}

// out[n] = sum_t relu(h[n,t]) * fc_w[t] + fc_b ; one 256-thread block per node
__global__ void final_k(const ushort* __restrict__ hH, const ushort* __restrict__ hL,
                        const void* fcw, const void* fcb,
                        void* out, const int* flags, int N) {
    const int n = blockIdx.x;
    const int t = threadIdx.x;
    const int isbf = flags[0];
    const size_t off = (size_t)n * HDIM + t;
    float v = fmaxf(bs2f(hH[off]) + bs2f(hL[off]), 0.f) * ldf(fcw, t, isbf);
#pragma unroll
    for (int offx = 32; offx >= 1; offx >>= 1) v += __shfl_down(v, offx);
    __shared__ float red[4];
    if ((t & 63) == 0) red[t >> 6] = v;
    __syncthreads();
    if (t == 0) {
        const float s = red[0] + red[1] + red[2] + red[3] + ldf(fcb, 0, isbf);
        if (isbf) ((__hip_bfloat16*)out)[n] = __float2bfloat16(s);
        else      ((float*)out)[n] = s;
    }
}

extern "C" void kernel_launch(void* const* d_in, const int* in_sizes, int n_in,
                              void* d_out, int out_size, void* d_ws, size_t ws_size,
                              hipStream_t stream) {
    const int H = HDIM;
    const int N = in_sizes[0] / H;       // 50000
    const int E = in_sizes[2];           // 800000
    const int L = in_sizes[3] / (H * H); // 5
    const size_t NH = (size_t)N * H;
    const int NB = (N + 255) / 256;

    char* base = (char*)d_ws;
    int*  flags = (int*)base;                         // 64 B
    char* regA  = base + 64;                          // NH*4 B (h planes / m)
    char* regB  = regA + NH * 4;                      // NH*4 B
    ushort* aggH = (ushort*)(regB + NH * 4);          // NH
    ushort* aggL = aggH + NH;                         // NH
    ushort* WtH  = aggL + NH;                         // L*65536
    ushort* WtL  = WtH + (size_t)L * 65536;
    ushort* WihH = WtL + (size_t)L * 65536;           // 196608
    ushort* WihL = WihH + 196608;
    ushort* WhhH = WihL + 196608;
    ushort* WhhL = WhhH + 196608;
    float* bsum  = (float*)(WhhL + 196608);           // 512
    float* bni   = bsum + 512;                        // 256
    float* bnh   = bni + 256;                         // 256
    int* ptr     = (int*)(bnh + 256);                 // N+1
    int* cursor  = ptr + (N + 1);                     // N
    int* bsumN   = cursor + N;                        // NB
    int* srcs    = bsumN + NB;                        // E
    float* wse   = (float*)(srcs + E);                // E
    // total ~= 165 MiB

    detect_k<<<dim3(1), dim3(64), 0, stream>>>(d_in[0], d_in[1], flags);
    conv_h0_k<<<dim3((unsigned)((NH + 255) / 256)), dim3(256), 0, stream>>>(
        d_in[0], (ushort*)regA, (ushort*)regA + NH, flags, NH);
    prep_k<<<dim3((L * 65536 + 255) / 256), dim3(256), 0, stream>>>(
        d_in[3], d_in[4], d_in[5], d_in[6], d_in[7],
        WtH, WtL, WihH, WihL, WhhH, WhhL, bsum, bni, bnh, flags, L);

    zero_int_k<<<dim3(NB), dim3(256), 0, stream>>>(cursor, N);
    count_k<<<dim3((E + 255) / 256), dim3(256), 0, stream>>>(d_in[1], cursor, flags, E);
    scan1_k<<<dim3(NB), dim3(256), 0, stream>>>(cursor, ptr, bsumN, N);
    scan2_k<<<dim3(1), dim3(256), 0, stream>>>(bsumN, NB);
    scan3_k<<<dim3(NB), dim3(256), 0, stream>>>(ptr, cursor, bsumN, N, E);
    fill_k<<<dim3((E + 255) / 256), dim3(256), 0, stream>>>(
        d_in[1], d_in[2], cursor, srcs, wse, flags, E);

    const dim3 blk(256);
    const int gm = (N + 63) / 64;
    char* regH = regA;  // current h (hi/lo planes)
    char* regM = regB;  // m (f32), later h_new planes
    for (int l = 0; l < L; ++l) {
        ushort* hH = (ushort*)regH;
        ushort* hL = hH + NH;
        mfma_gemm1_k<<<dim3(gm, 4), blk, 0, stream>>>(
            hH, hL, WtH + (size_t)l * 65536, WtL + (size_t)l * 65536,
            (float*)regM, flags, N);
        spmm_k<<<dim3((N + 3) / 4), blk, 0, stream>>>(
            (const float*)regM, ptr, srcs, wse, aggH, aggL, N);
        mfma_gates_k<<<dim3(gm, 4), blk, 0, stream>>>(
            aggH, aggL, hH, hL, WihH, WihL, WhhH, WhhL, bsum, bni, bnh,
            (ushort*)regM, (ushort*)regM + NH, flags, N);
        char* t = regH; regH = regM; regM = t;
    }
    final_k<<<dim3(N), blk, 0, stream>>>(
        (ushort*)regH, (ushort*)regH + NH, d_in[8], d_in[9], d_out, flags, N);
}

// Round 5
// 3307.035 us; speedup vs baseline: 5.1646x; 1.3940x over previous
//
#include <hip/hip_runtime.h>
#include <hip/hip_bf16.h>
#include <math.h>

// GGNN: L=5 layers of { m = h@W_l ; agg = scatter_add(ew * m[src] -> dst) ;
//                       h = GRUCell(agg, h) } then out = relu(h)@fc_w^T + fc_b
// H=256, N=50000, E=800000.
//
// R4 lesson: no-LDS MFMA kernels were latency-bound (MfmaUtil 7%, ~2 loads in
// flight: 64 acc VGPRs left no room to pipeline the 24 per-wave weight-frag
// global loads per K-chunk). R5: canonical LDS-tiled MFMA GEMM — per K-chunk
// the block stages A-planes + all 6 weight strips into LDS (weights once per
// block, not per wave), waves compute via ds_read_b128 (+40-half padded rows:
// 2-way bank aliasing only, which is free). Staged data holds no VGPRs.

#define HDIM 256

using bf16x8 = __attribute__((ext_vector_type(8))) short;
using f32x4  = __attribute__((ext_vector_type(4))) float;

__device__ __forceinline__ bf16x8 ldfrag(const ushort* p) {
    union { uint4 u; bf16x8 f; } x;
    x.u = *(const uint4*)p;
    return x.f;
}
#define MFMA(a, b, c) __builtin_amdgcn_mfma_f32_16x16x32_bf16((a), (b), (c), 0, 0, 0)

__device__ __forceinline__ float ldf(const void* p, size_t i, int isbf) {
    if (isbf) return __bfloat162float(((const __hip_bfloat16*)p)[i]);
    return ((const float*)p)[i];
}
__device__ __forceinline__ ushort f2bs(float v) {
    __hip_bfloat16 b = __float2bfloat16(v);
    return *(ushort*)&b;
}
__device__ __forceinline__ float bs2f(ushort u) {
    __hip_bfloat16 b = *(__hip_bfloat16*)&u;
    return __bfloat162float(b);
}

// flags[0] = 1 if float tensors are bf16, 0 if f32
// flags[1] = 1 if edge_index is int64, 0 if int32
__global__ void detect_k(const void* x, const void* ei, int* flags) {
    if (blockIdx.x == 0 && threadIdx.x == 0) {
        const __hip_bfloat16* xb = (const __hip_bfloat16*)x;
        int isbf = 1;
        for (int i = 0; i < 1024; ++i) {
            float v = fabsf(__bfloat162float(xb[i]));
            if (!(v < 1e6f)) { isbf = 0; break; }
        }
        flags[0] = isbf;
        const int* e32 = (const int*)ei;
        int orv = e32[1] | e32[3] | e32[5] | e32[7] | e32[9] | e32[11];
        flags[1] = (orv == 0) ? 1 : 0;
    }
}

// x -> h hi/lo planes
__global__ void conv_h0_k(const void* x, ushort* hH, ushort* hL,
                          const int* flags, size_t n) {
    size_t i = (size_t)blockIdx.x * blockDim.x + threadIdx.x;
    if (i >= n) return;
    const float v = ldf(x, i, flags[0]);
    const ushort h = f2bs(v);
    hH[i] = h;
    hL[i] = f2bs(v - bs2f(h));
}

// Weight planes. Wt[l][j][k] = weight[l][k][j] (NT form). Wih/Whh direct
// [768][256] copies (gate order r,z,n). All split hi/lo. Biases f32.
__global__ void prep_k(const void* w, const void* wih, const void* whh,
                       const void* bih, const void* bhh,
                       ushort* WtH, ushort* WtL, ushort* WihH, ushort* WihL,
                       ushort* WhhH, ushort* WhhL,
                       float* bsum, float* bni, float* bnh,
                       const int* flags, int L) {
    int i = blockIdx.x * blockDim.x + threadIdx.x;
    int isbf = flags[0];
    if (i < L * 65536) {
        int l = i >> 16, rem = i & 65535;
        int j = rem >> 8, k = rem & 255;
        float v = ldf(w, ((size_t)l << 16) + (size_t)k * 256 + j, isbf);
        ushort h = f2bs(v);
        WtH[i] = h; WtL[i] = f2bs(v - bs2f(h));
    }
    if (i < 196608) {
        float a = ldf(wih, i, isbf);
        ushort ah = f2bs(a);
        WihH[i] = ah; WihL[i] = f2bs(a - bs2f(ah));
        float b = ldf(whh, i, isbf);
        ushort bh = f2bs(b);
        WhhH[i] = bh; WhhL[i] = f2bs(b - bs2f(bh));
    }
    if (i < 512) bsum[i] = ldf(bih, i, isbf) + ldf(bhh, i, isbf);
    if (i < 256) {
        bni[i] = ldf(bih, 512 + i, isbf);
        bnh[i] = ldf(bhh, 512 + i, isbf);
    }
}

// ---------------- CSR build (by dst), once per call ----------------

__global__ void zero_int_k(int* p, int n) {
    int i = blockIdx.x * blockDim.x + threadIdx.x;
    if (i < n) p[i] = 0;
}

__global__ void count_k(const void* ei, int* cnt, const int* flags, int E) {
    int e = blockIdx.x * blockDim.x + threadIdx.x;
    if (e >= E) return;
    const int* e32 = (const int*)ei;
    int d = flags[1] ? e32[2 * ((size_t)E + e)] : e32[(size_t)E + e];
    atomicAdd(&cnt[d], 1);
}

__global__ __launch_bounds__(256)
void scan1_k(const int* cnt, int* ptr, int* bsumN, int N) {
    __shared__ int s[256];
    const int t = threadIdx.x;
    const int gid = blockIdx.x * 256 + t;
    int v = (gid < N) ? cnt[gid] : 0;
    const int own = v;
    s[t] = v;
    __syncthreads();
#pragma unroll
    for (int off = 1; off < 256; off <<= 1) {
        int add = (t >= off) ? s[t - off] : 0;
        __syncthreads();
        s[t] += add;
        __syncthreads();
    }
    if (gid < N) ptr[gid] = s[t] - own;
    if (t == 255) bsumN[blockIdx.x] = s[255];
}

__global__ __launch_bounds__(256)
void scan2_k(int* bsumN, int NB) {
    __shared__ int s[256];
    __shared__ int carry;
    const int t = threadIdx.x;
    if (t == 0) carry = 0;
    __syncthreads();
    for (int base = 0; base < NB; base += 256) {
        const int i = base + t;
        int v = (i < NB) ? bsumN[i] : 0;
        const int own = v;
        s[t] = v;
        __syncthreads();
#pragma unroll
        for (int off = 1; off < 256; off <<= 1) {
            int add = (t >= off) ? s[t - off] : 0;
            __syncthreads();
            s[t] += add;
            __syncthreads();
        }
        if (i < NB) bsumN[i] = carry + s[t] - own;
        __syncthreads();
        if (t == 0) carry += s[255];
        __syncthreads();
    }
}

__global__ void scan3_k(int* ptr, int* cursor, const int* bsumN, int N, int E) {
    const int gid = blockIdx.x * 256 + threadIdx.x;
    if (gid < N) {
        const int p = ptr[gid] + bsumN[blockIdx.x];
        ptr[gid] = p;
        cursor[gid] = p;
    }
    if (gid == 0) ptr[N] = E;
}

__global__ void fill_k(const void* ei, const void* ew, int* cursor,
                       int* srcs, float* wse, const int* flags, int E) {
    int e = blockIdx.x * blockDim.x + threadIdx.x;
    if (e >= E) return;
    const int* e32 = (const int*)ei;
    int s, d;
    if (flags[1]) { s = e32[2 * (size_t)e]; d = e32[2 * ((size_t)E + e)]; }
    else          { s = e32[e];             d = e32[(size_t)E + e]; }
    const int p = atomicAdd(&cursor[d], 1);
    srcs[p] = s;
    wse[p] = ldf(ew, e, flags[0]);
}

// ---------------- SpMM gather: agg[d] = sum_j w_j * m[src_j] ----------------
__global__ __launch_bounds__(256)
void spmm_k(const float* __restrict__ m, const int* __restrict__ ptr,
            const int* __restrict__ srcs, const float* __restrict__ wse,
            ushort* __restrict__ aggH, ushort* __restrict__ aggL, int N) {
    const int node = blockIdx.x * 4 + (threadIdx.x >> 6);
    if (node >= N) return;
    const int lane4 = (threadIdx.x & 63) << 2;
    const int p0 = ptr[node], p1 = ptr[node + 1];
    float4 acc = make_float4(0.f, 0.f, 0.f, 0.f);
    int j = p0;
    for (; j + 1 < p1; j += 2) {
        const int s0 = srcs[j], s1 = srcs[j + 1];
        const float w0 = wse[j], w1 = wse[j + 1];
        const float4 v0 = *(const float4*)&m[(size_t)s0 * HDIM + lane4];
        const float4 v1 = *(const float4*)&m[(size_t)s1 * HDIM + lane4];
        acc.x = fmaf(w0, v0.x, acc.x); acc.y = fmaf(w0, v0.y, acc.y);
        acc.z = fmaf(w0, v0.z, acc.z); acc.w = fmaf(w0, v0.w, acc.w);
        acc.x = fmaf(w1, v1.x, acc.x); acc.y = fmaf(w1, v1.y, acc.y);
        acc.z = fmaf(w1, v1.z, acc.z); acc.w = fmaf(w1, v1.w, acc.w);
    }
    if (j < p1) {
        const int s0 = srcs[j];
        const float w0 = wse[j];
        const float4 v0 = *(const float4*)&m[(size_t)s0 * HDIM + lane4];
        acc.x = fmaf(w0, v0.x, acc.x); acc.y = fmaf(w0, v0.y, acc.y);
        acc.z = fmaf(w0, v0.z, acc.z); acc.w = fmaf(w0, v0.w, acc.w);
    }
    ushort4 hi, lo;
    hi.x = f2bs(acc.x); lo.x = f2bs(acc.x - bs2f(hi.x));
    hi.y = f2bs(acc.y); lo.y = f2bs(acc.y - bs2f(hi.y));
    hi.z = f2bs(acc.z); lo.z = f2bs(acc.z - bs2f(hi.z));
    hi.w = f2bs(acc.w); lo.w = f2bs(acc.w - bs2f(hi.w));
    *(ushort4*)&aggH[(size_t)node * HDIM + lane4] = hi;
    *(ushort4*)&aggL[(size_t)node * HDIM + lane4] = lo;
}

// ---------------- LDS-tiled MFMA GEMMs ----------------
// Block: 256 threads = 4 waves; tile 64 rows x 64 cols; K-chunks of 32.
// LDS rows padded to 40 halves (80 B): ds_read_b128 lane offsets 80*lm+16*lq
// cover all 8 bank groups exactly twice (2-way aliasing = free).
// A-frag: lane(lm,lq) = row lm, k lq*8..+7. B-frag (NT): col lm, same k.
// C/D: col = lane&15, row = (lane>>4)*4 + reg.

#define ROWP 40  // padded LDS row stride, halves

// m = h @ Wt^T (2 A-planes, 1 weight; lo-weight via global when f32 inputs)
__global__ __launch_bounds__(256)
void mfma_gemm1_k(const ushort* __restrict__ hH, const ushort* __restrict__ hL,
                  const ushort* __restrict__ WH, const ushort* __restrict__ WL,
                  float* __restrict__ m, const int* __restrict__ flags, int N) {
    __shared__ ushort sm[3 * 64 * ROWP];  // planes hH,hL then W
    const int tid = threadIdx.x;
    const int lane = tid & 63;
    const int w16 = (tid >> 6) * 16;
    const int r0 = blockIdx.x * 64, c0 = blockIdx.y * 64;
    const int lm = lane & 15, lq = lane >> 4;
    const int sr = tid >> 2, skq = tid & 3;   // staging row/col + k-quad
    const int fullsplit = !flags[0];
    f32x4 acc[4];
#pragma unroll
    for (int cb = 0; cb < 4; ++cb) acc[cb] = (f32x4){0.f, 0.f, 0.f, 0.f};

    const ushort* Asrc[2] = {hH, hL};
    for (int ks = 0; ks < 256; ks += 32) {
        __syncthreads();
#pragma unroll
        for (int j = 0; j < 2; ++j) {
            uint4 v = make_uint4(0, 0, 0, 0);
            if (r0 + sr < N)
                v = *(const uint4*)&Asrc[j][(size_t)(r0 + sr) * 256 + ks + skq * 8];
            *(uint4*)&sm[j * 64 * ROWP + sr * ROWP + skq * 8] = v;
        }
        {
            uint4 v = *(const uint4*)&WH[(size_t)(c0 + sr) * 256 + ks + skq * 8];
            *(uint4*)&sm[2 * 64 * ROWP + sr * ROWP + skq * 8] = v;
        }
        __syncthreads();
        const int ab = (w16 + lm) * ROWP + lq * 8;
        const bf16x8 ah = ldfrag(&sm[ab]);
        const bf16x8 al = ldfrag(&sm[64 * ROWP + ab]);
#pragma unroll
        for (int cb = 0; cb < 4; ++cb) {
            const bf16x8 w = ldfrag(&sm[2 * 64 * ROWP + (cb * 16 + lm) * ROWP + lq * 8]);
            acc[cb] = MFMA(ah, w, acc[cb]);
            acc[cb] = MFMA(al, w, acc[cb]);
            if (fullsplit) {
                const bf16x8 wl = ldfrag(&WL[(size_t)(c0 + cb * 16 + lm) * 256 + ks + lq * 8]);
                acc[cb] = MFMA(ah, wl, acc[cb]);
            }
        }
    }
#pragma unroll
    for (int cb = 0; cb < 4; ++cb) {
        const int col = c0 + cb * 16 + lm;
#pragma unroll
        for (int v = 0; v < 4; ++v) {
            const int row = blockIdx.x * 64 + w16 + lq * 4 + v;
            if (row < N) m[(size_t)row * 256 + col] = acc[cb][v];
        }
    }
}

// Fused GRU gates + update, LDS-tiled. Stages 4 A-planes + 6 weight strips
// per K-chunk; 48 MFMAs/wave/chunk; epilogue does sigmoid/tanh/mix.
__global__ __launch_bounds__(256)
void mfma_gates_k(const ushort* __restrict__ agH, const ushort* __restrict__ agL,
                  const ushort* __restrict__ hoH, const ushort* __restrict__ hoL,
                  const ushort* __restrict__ WihH, const ushort* __restrict__ WihL,
                  const ushort* __restrict__ WhhH, const ushort* __restrict__ WhhL,
                  const float* __restrict__ bsum, const float* __restrict__ bni,
                  const float* __restrict__ bnh,
                  ushort* __restrict__ hnH, ushort* __restrict__ hnL,
                  const int* __restrict__ flags, int N) {
    __shared__ ushort sm[10 * 64 * ROWP];  // 4 A-planes + 6 weight strips (50 KB)
    const int tid = threadIdx.x;
    const int lane = tid & 63;
    const int w16 = (tid >> 6) * 16;
    const int r0 = blockIdx.x * 64, c0 = blockIdx.y * 64;
    const int lm = lane & 15, lq = lane >> 4;
    const int sr = tid >> 2, skq = tid & 3;
    const int fullsplit = !flags[0];
    f32x4 aR[4], aZ[4], aNI[4], aNH[4];
#pragma unroll
    for (int cb = 0; cb < 4; ++cb) {
        aR[cb] = (f32x4){0.f, 0.f, 0.f, 0.f};
        aZ[cb] = (f32x4){0.f, 0.f, 0.f, 0.f};
        aNI[cb] = (f32x4){0.f, 0.f, 0.f, 0.f};
        aNH[cb] = (f32x4){0.f, 0.f, 0.f, 0.f};
    }

    const ushort* Asrc[4] = {agH, agL, hoH, hoL};
    const ushort* Wsrc[6] = {WihH, WihH + 65536, WihH + 131072,
                             WhhH, WhhH + 65536, WhhH + 131072};
    for (int ks = 0; ks < 256; ks += 32) {
        __syncthreads();
#pragma unroll
        for (int j = 0; j < 4; ++j) {
            uint4 v = make_uint4(0, 0, 0, 0);
            if (r0 + sr < N)
                v = *(const uint4*)&Asrc[j][(size_t)(r0 + sr) * 256 + ks + skq * 8];
            *(uint4*)&sm[j * 64 * ROWP + sr * ROWP + skq * 8] = v;
        }
#pragma unroll
        for (int j = 0; j < 6; ++j) {
            uint4 v = *(const uint4*)&Wsrc[j][(size_t)(c0 + sr) * 256 + ks + skq * 8];
            *(uint4*)&sm[(4 + j) * 64 * ROWP + sr * ROWP + skq * 8] = v;
        }
        __syncthreads();
        const int ab = (w16 + lm) * ROWP + lq * 8;
        const bf16x8 ah = ldfrag(&sm[ab]);
        const bf16x8 al = ldfrag(&sm[1 * 64 * ROWP + ab]);
        const bf16x8 hh = ldfrag(&sm[2 * 64 * ROWP + ab]);
        const bf16x8 hl = ldfrag(&sm[3 * 64 * ROWP + ab]);
#pragma unroll
        for (int cb = 0; cb < 4; ++cb) {
            const int wb = (cb * 16 + lm) * ROWP + lq * 8;
            const bf16x8 wri = ldfrag(&sm[4 * 64 * ROWP + wb]);
            const bf16x8 wzi = ldfrag(&sm[5 * 64 * ROWP + wb]);
            const bf16x8 wni = ldfrag(&sm[6 * 64 * ROWP + wb]);
            const bf16x8 wrh = ldfrag(&sm[7 * 64 * ROWP + wb]);
            const bf16x8 wzh = ldfrag(&sm[8 * 64 * ROWP + wb]);
            const bf16x8 wnh = ldfrag(&sm[9 * 64 * ROWP + wb]);
            aR[cb] = MFMA(ah, wri, aR[cb]);
            aZ[cb] = MFMA(ah, wzi, aZ[cb]);
            aNI[cb] = MFMA(ah, wni, aNI[cb]);
            aNH[cb] = MFMA(hh, wnh, aNH[cb]);
            aR[cb] = MFMA(al, wri, aR[cb]);
            aZ[cb] = MFMA(al, wzi, aZ[cb]);
            aNI[cb] = MFMA(al, wni, aNI[cb]);
            aNH[cb] = MFMA(hl, wnh, aNH[cb]);
            aR[cb] = MFMA(hh, wrh, aR[cb]);
            aZ[cb] = MFMA(hh, wzh, aZ[cb]);
            aR[cb] = MFMA(hl, wrh, aR[cb]);
            aZ[cb] = MFMA(hl, wzh, aZ[cb]);
            if (fullsplit) {
                const size_t wr = (size_t)(c0 + cb * 16 + lm) * 256 + ks + lq * 8;
                aR[cb] = MFMA(ah, ldfrag(WihL + wr), aR[cb]);
                aR[cb] = MFMA(hh, ldfrag(WhhL + wr), aR[cb]);
                aZ[cb] = MFMA(ah, ldfrag(WihL + wr + 65536), aZ[cb]);
                aZ[cb] = MFMA(hh, ldfrag(WhhL + wr + 65536), aZ[cb]);
                aNI[cb] = MFMA(ah, ldfrag(WihL + wr + 131072), aNI[cb]);
                aNH[cb] = MFMA(hh, ldfrag(WhhL + wr + 131072), aNH[cb]);
            }
        }
    }
#pragma unroll
    for (int cb = 0; cb < 4; ++cb) {
        const int col = c0 + cb * 16 + lm;
        const float rb = bsum[col];
        const float zb = bsum[256 + col];
        const float ib = bni[col];
        const float hb = bnh[col];
#pragma unroll
        for (int v = 0; v < 4; ++v) {
            const int row = blockIdx.x * 64 + w16 + lq * 4 + v;
            if (row < N) {
                const size_t off = (size_t)row * 256 + col;
                const float hold = bs2f(hoH[off]) + bs2f(hoL[off]);
                const float r = 1.f / (1.f + expf(-(aR[cb][v] + rb)));
                const float z = 1.f / (1.f + expf(-(aZ[cb][v] + zb)));
                const float nn = tanhf(aNI[cb][v] + ib + r * (aNH[cb][v] + hb));
                const float hv = (1.f - z) * nn + z * hold;
                const ushort hi = f2bs(hv);
                hnH[off] = hi;
                hnL[off] = f2bs(hv - bs2f(hi));
            }
        }
    }
}

// out[n] = sum_t relu(h[n,t]) * fc_w[t] + fc_b ; one 256-thread block per node
__global__ void final_k(const ushort* __restrict__ hH, const ushort* __restrict__ hL,
                        const void* fcw, const void* fcb,
                        void* out, const int* flags, int N) {
    const int n = blockIdx.x;
    const int t = threadIdx.x;
    const int isbf = flags[0];
    const size_t off = (size_t)n * HDIM + t;
    float v = fmaxf(bs2f(hH[off]) + bs2f(hL[off]), 0.f) * ldf(fcw, t, isbf);
#pragma unroll
    for (int offx = 32; offx >= 1; offx >>= 1) v += __shfl_down(v, offx);
    __shared__ float red[4];
    if ((t & 63) == 0) red[t >> 6] = v;
    __syncthreads();
    if (t == 0) {
        const float s = red[0] + red[1] + red[2] + red[3] + ldf(fcb, 0, isbf);
        if (isbf) ((__hip_bfloat16*)out)[n] = __float2bfloat16(s);
        else      ((float*)out)[n] = s;
    }
}

extern "C" void kernel_launch(void* const* d_in, const int* in_sizes, int n_in,
                              void* d_out, int out_size, void* d_ws, size_t ws_size,
                              hipStream_t stream) {
    const int H = HDIM;
    const int N = in_sizes[0] / H;       // 50000
    const int E = in_sizes[2];           // 800000
    const int L = in_sizes[3] / (H * H); // 5
    const size_t NH = (size_t)N * H;
    const int NB = (N + 255) / 256;

    char* base = (char*)d_ws;
    int*  flags = (int*)base;                         // 64 B
    char* regA  = base + 64;                          // NH*4 B (h planes / m)
    char* regB  = regA + NH * 4;                      // NH*4 B
    ushort* aggH = (ushort*)(regB + NH * 4);          // NH
    ushort* aggL = aggH + NH;                         // NH
    ushort* WtH  = aggL + NH;                         // L*65536
    ushort* WtL  = WtH + (size_t)L * 65536;
    ushort* WihH = WtL + (size_t)L * 65536;           // 196608
    ushort* WihL = WihH + 196608;
    ushort* WhhH = WihL + 196608;
    ushort* WhhL = WhhH + 196608;
    float* bsum  = (float*)(WhhL + 196608);           // 512
    float* bni   = bsum + 512;                        // 256
    float* bnh   = bni + 256;                         // 256
    int* ptr     = (int*)(bnh + 256);                 // N+1
    int* cursor  = ptr + (N + 1);                     // N
    int* bsumN   = cursor + N;                        // NB
    int* srcs    = bsumN + NB;                        // E
    float* wse   = (float*)(srcs + E);                // E
    // total ~= 165 MiB

    detect_k<<<dim3(1), dim3(64), 0, stream>>>(d_in[0], d_in[1], flags);
    conv_h0_k<<<dim3((unsigned)((NH + 255) / 256)), dim3(256), 0, stream>>>(
        d_in[0], (ushort*)regA, (ushort*)regA + NH, flags, NH);
    prep_k<<<dim3((L * 65536 + 255) / 256), dim3(256), 0, stream>>>(
        d_in[3], d_in[4], d_in[5], d_in[6], d_in[7],
        WtH, WtL, WihH, WihL, WhhH, WhhL, bsum, bni, bnh, flags, L);

    zero_int_k<<<dim3(NB), dim3(256), 0, stream>>>(cursor, N);
    count_k<<<dim3((E + 255) / 256), dim3(256), 0, stream>>>(d_in[1], cursor, flags, E);
    scan1_k<<<dim3(NB), dim3(256), 0, stream>>>(cursor, ptr, bsumN, N);
    scan2_k<<<dim3(1), dim3(256), 0, stream>>>(bsumN, NB);
    scan3_k<<<dim3(NB), dim3(256), 0, stream>>>(ptr, cursor, bsumN, N, E);
    fill_k<<<dim3((E + 255) / 256), dim3(256), 0, stream>>>(
        d_in[1], d_in[2], cursor, srcs, wse, flags, E);

    const dim3 blk(256);
    const int gm = (N + 63) / 64;
    char* regH = regA;  // current h (hi/lo planes)
    char* regM = regB;  // m (f32), later h_new planes
    for (int l = 0; l < L; ++l) {
        ushort* hH = (ushort*)regH;
        ushort* hL = hH + NH;
        mfma_gemm1_k<<<dim3(gm, 4), blk, 0, stream>>>(
            hH, hL, WtH + (size_t)l * 65536, WtL + (size_t)l * 65536,
            (float*)regM, flags, N);
        spmm_k<<<dim3((N + 3) / 4), blk, 0, stream>>>(
            (const float*)regM, ptr, srcs, wse, aggH, aggL, N);
        mfma_gates_k<<<dim3(gm, 4), blk, 0, stream>>>(
            aggH, aggL, hH, hL, WihH, WihL, WhhH, WhhL, bsum, bni, bnh,
            (ushort*)regM, (ushort*)regM + NH, flags, N);
        char* t = regH; regH = regM; regM = t;
    }
    final_k<<<dim3(N), blk, 0, stream>>>(
        (ushort*)regH, (ushort*)regH + NH, d_in[8], d_in[9], d_out, flags, N);
}

// Round 6
// 3295.532 us; speedup vs baseline: 5.1826x; 1.0035x over previous
//
#include <hip/hip_runtime.h>
#include <hip/hip_bf16.h>
#include <math.h>

// GGNN: L=5 layers of { m = h@W_l ; agg = scatter_add(ew * m[src] -> dst) ;
//                       h = GRUCell(agg, h) } then out = relu(h)@fc_w^T + fc_b
// H=256, N=50000, E=800000.
//
// R5 lesson: LDS-tiled MFMA was still latency-bound (MfmaUtil 11%, occ 22%):
// 10 uint4 global->VGPR->LDS staging loads per thread per chunk serialized on
// register pressure, and 50KB LDS capped residency at 3 blocks/CU. R6:
// weights staged via async __builtin_amdgcn_global_load_lds (width 16, no
// VGPR round-trip; lane i -> ldsbase+16i matches an unpadded [64][32]-half
// tile), A fragments read directly global->register (per-wave private rows,
// read once per block). Gates LDS 50->24 KB.

#define HDIM 256

using bf16x8 = __attribute__((ext_vector_type(8))) short;
using f32x4  = __attribute__((ext_vector_type(4))) float;

__device__ __forceinline__ bf16x8 ldfrag(const ushort* p) {
    union { uint4 u; bf16x8 f; } x;
    x.u = *(const uint4*)p;
    return x.f;
}
#define MFMA(a, b, c) __builtin_amdgcn_mfma_f32_16x16x32_bf16((a), (b), (c), 0, 0, 0)
// async global->LDS, 16B per lane; LDS dest = wave-uniform base + lane*16
#define GLD16(g, l)                                                            \
    __builtin_amdgcn_global_load_lds(                                          \
        (const __attribute__((address_space(1))) void*)(g),                    \
        (__attribute__((address_space(3))) void*)(l), 16, 0, 0)

__device__ __forceinline__ float ldf(const void* p, size_t i, int isbf) {
    if (isbf) return __bfloat162float(((const __hip_bfloat16*)p)[i]);
    return ((const float*)p)[i];
}
__device__ __forceinline__ ushort f2bs(float v) {
    __hip_bfloat16 b = __float2bfloat16(v);
    return *(ushort*)&b;
}
__device__ __forceinline__ float bs2f(ushort u) {
    __hip_bfloat16 b = *(__hip_bfloat16*)&u;
    return __bfloat162float(b);
}

// flags[0] = 1 if float tensors are bf16, 0 if f32
// flags[1] = 1 if edge_index is int64, 0 if int32
__global__ void detect_k(const void* x, const void* ei, int* flags) {
    if (blockIdx.x == 0 && threadIdx.x == 0) {
        const __hip_bfloat16* xb = (const __hip_bfloat16*)x;
        int isbf = 1;
        for (int i = 0; i < 1024; ++i) {
            float v = fabsf(__bfloat162float(xb[i]));
            if (!(v < 1e6f)) { isbf = 0; break; }
        }
        flags[0] = isbf;
        const int* e32 = (const int*)ei;
        int orv = e32[1] | e32[3] | e32[5] | e32[7] | e32[9] | e32[11];
        flags[1] = (orv == 0) ? 1 : 0;
    }
}

// x -> h hi/lo planes
__global__ void conv_h0_k(const void* x, ushort* hH, ushort* hL,
                          const int* flags, size_t n) {
    size_t i = (size_t)blockIdx.x * blockDim.x + threadIdx.x;
    if (i >= n) return;
    const float v = ldf(x, i, flags[0]);
    const ushort h = f2bs(v);
    hH[i] = h;
    hL[i] = f2bs(v - bs2f(h));
}

// Weight planes. Wt[l][j][k] = weight[l][k][j] (NT form). Wih/Whh direct
// [768][256] copies (gate order r,z,n). All split hi/lo. Biases f32.
__global__ void prep_k(const void* w, const void* wih, const void* whh,
                       const void* bih, const void* bhh,
                       ushort* WtH, ushort* WtL, ushort* WihH, ushort* WihL,
                       ushort* WhhH, ushort* WhhL,
                       float* bsum, float* bni, float* bnh,
                       const int* flags, int L) {
    int i = blockIdx.x * blockDim.x + threadIdx.x;
    int isbf = flags[0];
    if (i < L * 65536) {
        int l = i >> 16, rem = i & 65535;
        int j = rem >> 8, k = rem & 255;
        float v = ldf(w, ((size_t)l << 16) + (size_t)k * 256 + j, isbf);
        ushort h = f2bs(v);
        WtH[i] = h; WtL[i] = f2bs(v - bs2f(h));
    }
    if (i < 196608) {
        float a = ldf(wih, i, isbf);
        ushort ah = f2bs(a);
        WihH[i] = ah; WihL[i] = f2bs(a - bs2f(ah));
        float b = ldf(whh, i, isbf);
        ushort bh = f2bs(b);
        WhhH[i] = bh; WhhL[i] = f2bs(b - bs2f(bh));
    }
    if (i < 512) bsum[i] = ldf(bih, i, isbf) + ldf(bhh, i, isbf);
    if (i < 256) {
        bni[i] = ldf(bih, 512 + i, isbf);
        bnh[i] = ldf(bhh, 512 + i, isbf);
    }
}

// ---------------- CSR build (by dst), once per call ----------------

__global__ void zero_int_k(int* p, int n) {
    int i = blockIdx.x * blockDim.x + threadIdx.x;
    if (i < n) p[i] = 0;
}

__global__ void count_k(const void* ei, int* cnt, const int* flags, int E) {
    int e = blockIdx.x * blockDim.x + threadIdx.x;
    if (e >= E) return;
    const int* e32 = (const int*)ei;
    int d = flags[1] ? e32[2 * ((size_t)E + e)] : e32[(size_t)E + e];
    atomicAdd(&cnt[d], 1);
}

__global__ __launch_bounds__(256)
void scan1_k(const int* cnt, int* ptr, int* bsumN, int N) {
    __shared__ int s[256];
    const int t = threadIdx.x;
    const int gid = blockIdx.x * 256 + t;
    int v = (gid < N) ? cnt[gid] : 0;
    const int own = v;
    s[t] = v;
    __syncthreads();
#pragma unroll
    for (int off = 1; off < 256; off <<= 1) {
        int add = (t >= off) ? s[t - off] : 0;
        __syncthreads();
        s[t] += add;
        __syncthreads();
    }
    if (gid < N) ptr[gid] = s[t] - own;
    if (t == 255) bsumN[blockIdx.x] = s[255];
}

__global__ __launch_bounds__(256)
void scan2_k(int* bsumN, int NB) {
    __shared__ int s[256];
    __shared__ int carry;
    const int t = threadIdx.x;
    if (t == 0) carry = 0;
    __syncthreads();
    for (int base = 0; base < NB; base += 256) {
        const int i = base + t;
        int v = (i < NB) ? bsumN[i] : 0;
        const int own = v;
        s[t] = v;
        __syncthreads();
#pragma unroll
        for (int off = 1; off < 256; off <<= 1) {
            int add = (t >= off) ? s[t - off] : 0;
            __syncthreads();
            s[t] += add;
            __syncthreads();
        }
        if (i < NB) bsumN[i] = carry + s[t] - own;
        __syncthreads();
        if (t == 0) carry += s[255];
        __syncthreads();
    }
}

__global__ void scan3_k(int* ptr, int* cursor, const int* bsumN, int N, int E) {
    const int gid = blockIdx.x * 256 + threadIdx.x;
    if (gid < N) {
        const int p = ptr[gid] + bsumN[blockIdx.x];
        ptr[gid] = p;
        cursor[gid] = p;
    }
    if (gid == 0) ptr[N] = E;
}

__global__ void fill_k(const void* ei, const void* ew, int* cursor,
                       int* srcs, float* wse, const int* flags, int E) {
    int e = blockIdx.x * blockDim.x + threadIdx.x;
    if (e >= E) return;
    const int* e32 = (const int*)ei;
    int s, d;
    if (flags[1]) { s = e32[2 * (size_t)e]; d = e32[2 * ((size_t)E + e)]; }
    else          { s = e32[e];             d = e32[(size_t)E + e]; }
    const int p = atomicAdd(&cursor[d], 1);
    srcs[p] = s;
    wse[p] = ldf(ew, e, flags[0]);
}

// ---------------- SpMM gather: agg[d] = sum_j w_j * m[src_j] ----------------
__global__ __launch_bounds__(256)
void spmm_k(const float* __restrict__ m, const int* __restrict__ ptr,
            const int* __restrict__ srcs, const float* __restrict__ wse,
            ushort* __restrict__ aggH, ushort* __restrict__ aggL, int N) {
    const int node = blockIdx.x * 4 + (threadIdx.x >> 6);
    if (node >= N) return;
    const int lane4 = (threadIdx.x & 63) << 2;
    const int p0 = ptr[node], p1 = ptr[node + 1];
    float4 acc = make_float4(0.f, 0.f, 0.f, 0.f);
    int j = p0;
    for (; j + 1 < p1; j += 2) {
        const int s0 = srcs[j], s1 = srcs[j + 1];
        const float w0 = wse[j], w1 = wse[j + 1];
        const float4 v0 = *(const float4*)&m[(size_t)s0 * HDIM + lane4];
        const float4 v1 = *(const float4*)&m[(size_t)s1 * HDIM + lane4];
        acc.x = fmaf(w0, v0.x, acc.x); acc.y = fmaf(w0, v0.y, acc.y);
        acc.z = fmaf(w0, v0.z, acc.z); acc.w = fmaf(w0, v0.w, acc.w);
        acc.x = fmaf(w1, v1.x, acc.x); acc.y = fmaf(w1, v1.y, acc.y);
        acc.z = fmaf(w1, v1.z, acc.z); acc.w = fmaf(w1, v1.w, acc.w);
    }
    if (j < p1) {
        const int s0 = srcs[j];
        const float w0 = wse[j];
        const float4 v0 = *(const float4*)&m[(size_t)s0 * HDIM + lane4];
        acc.x = fmaf(w0, v0.x, acc.x); acc.y = fmaf(w0, v0.y, acc.y);
        acc.z = fmaf(w0, v0.z, acc.z); acc.w = fmaf(w0, v0.w, acc.w);
    }
    ushort4 hi, lo;
    hi.x = f2bs(acc.x); lo.x = f2bs(acc.x - bs2f(hi.x));
    hi.y = f2bs(acc.y); lo.y = f2bs(acc.y - bs2f(hi.y));
    hi.z = f2bs(acc.z); lo.z = f2bs(acc.z - bs2f(hi.z));
    hi.w = f2bs(acc.w); lo.w = f2bs(acc.w - bs2f(hi.w));
    *(ushort4*)&aggH[(size_t)node * HDIM + lane4] = hi;
    *(ushort4*)&aggL[(size_t)node * HDIM + lane4] = lo;
}

// ---------------- MFMA GEMMs: async-LDS weights, direct-global A ----------
// Block: 256 threads = 4 waves; tile 64 rows x 64 cols; K-chunks of 32.
// Weight strip chunk tile in LDS: [64 rows][32 halves] unpadded; glds lane
// mapping lane=4*row+quad -> base + 16*lane matches exactly.
// A-frag: wave-private rows (w16+lm), direct 16B global loads.
// C/D: col = lane&15, row = (lane>>4)*4 + reg.

// m = h @ Wt^T
__global__ __launch_bounds__(256)
void mfma_gemm1_k(const ushort* __restrict__ hH, const ushort* __restrict__ hL,
                  const ushort* __restrict__ WH, const ushort* __restrict__ WL,
                  float* __restrict__ m, const int* __restrict__ flags, int N) {
    __shared__ ushort smW[64 * 32];  // 4 KB
    const int tid = threadIdx.x;
    const int lane = tid & 63;
    const int wvu = __builtin_amdgcn_readfirstlane(tid >> 6);
    const int w16 = wvu * 16;
    const int r0 = blockIdx.x * 64, c0 = blockIdx.y * 64;
    const int lm = lane & 15, lq = lane >> 4;
    const int srow = lane >> 2, squad = lane & 3;  // staging: lane = 4*row+quad
    const int fullsplit = !flags[0];
    const int ar = min(r0 + w16 + lm, N - 1);      // clamp keeps loads in-bounds
    f32x4 acc[4];
#pragma unroll
    for (int cb = 0; cb < 4; ++cb) acc[cb] = (f32x4){0.f, 0.f, 0.f, 0.f};

    for (int ks = 0; ks < 256; ks += 32) {
        const size_t wgoff = (size_t)(c0 + w16 + srow) * 256 + ks + squad * 8;
        GLD16(WH + wgoff, &smW[wvu * 512]);
        const size_t ao = (size_t)ar * 256 + ks + lq * 8;
        const bf16x8 ah = ldfrag(hH + ao);
        const bf16x8 al = ldfrag(hL + ao);
        __syncthreads();
#pragma unroll
        for (int cb = 0; cb < 4; ++cb) {
            const bf16x8 w = ldfrag(&smW[(cb * 16 + lm) * 32 + lq * 8]);
            acc[cb] = MFMA(ah, w, acc[cb]);
            acc[cb] = MFMA(al, w, acc[cb]);
            if (fullsplit) {
                const bf16x8 wl = ldfrag(&WL[(size_t)(c0 + cb * 16 + lm) * 256 + ks + lq * 8]);
                acc[cb] = MFMA(ah, wl, acc[cb]);
            }
        }
        __syncthreads();
    }
#pragma unroll
    for (int cb = 0; cb < 4; ++cb) {
        const int col = c0 + cb * 16 + lm;
#pragma unroll
        for (int v = 0; v < 4; ++v) {
            const int row = r0 + w16 + lq * 4 + v;
            if (row < N) m[(size_t)row * 256 + col] = acc[cb][v];
        }
    }
}

// Fused GRU gates + update. Stages 6 weight strips/chunk async into LDS
// (24 KB); A planes direct global->register; 48 MFMAs/wave/chunk; epilogue
// does sigmoid/tanh/mix and writes h_new hi/lo planes.
__global__ __launch_bounds__(256)
void mfma_gates_k(const ushort* __restrict__ agH, const ushort* __restrict__ agL,
                  const ushort* __restrict__ hoH, const ushort* __restrict__ hoL,
                  const ushort* __restrict__ WihH, const ushort* __restrict__ WihL,
                  const ushort* __restrict__ WhhH, const ushort* __restrict__ WhhL,
                  const float* __restrict__ bsum, const float* __restrict__ bni,
                  const float* __restrict__ bnh,
                  ushort* __restrict__ hnH, ushort* __restrict__ hnL,
                  const int* __restrict__ flags, int N) {
    __shared__ ushort smW[6 * 64 * 32];  // 24 KB: [strip][64 rows][32 halves]
    const int tid = threadIdx.x;
    const int lane = tid & 63;
    const int wvu = __builtin_amdgcn_readfirstlane(tid >> 6);
    const int w16 = wvu * 16;
    const int r0 = blockIdx.x * 64, c0 = blockIdx.y * 64;
    const int lm = lane & 15, lq = lane >> 4;
    const int srow = lane >> 2, squad = lane & 3;
    const int fullsplit = !flags[0];
    const int ar = min(r0 + w16 + lm, N - 1);
    f32x4 aR[4], aZ[4], aNI[4], aNH[4];
#pragma unroll
    for (int cb = 0; cb < 4; ++cb) {
        aR[cb] = (f32x4){0.f, 0.f, 0.f, 0.f};
        aZ[cb] = (f32x4){0.f, 0.f, 0.f, 0.f};
        aNI[cb] = (f32x4){0.f, 0.f, 0.f, 0.f};
        aNH[cb] = (f32x4){0.f, 0.f, 0.f, 0.f};
    }

    const ushort* Wsrc[6] = {WihH, WihH + 65536, WihH + 131072,
                             WhhH, WhhH + 65536, WhhH + 131072};
    for (int ks = 0; ks < 256; ks += 32) {
        const size_t wgoff = (size_t)(c0 + w16 + srow) * 256 + ks + squad * 8;
#pragma unroll
        for (int j = 0; j < 6; ++j)
            GLD16(Wsrc[j] + wgoff, &smW[j * 2048 + wvu * 512]);
        const size_t ao = (size_t)ar * 256 + ks + lq * 8;
        const bf16x8 ah = ldfrag(agH + ao);
        const bf16x8 al = ldfrag(agL + ao);
        const bf16x8 hh = ldfrag(hoH + ao);
        const bf16x8 hl = ldfrag(hoL + ao);
        __syncthreads();
#pragma unroll
        for (int cb = 0; cb < 4; ++cb) {
            const int wb = (cb * 16 + lm) * 32 + lq * 8;
            const bf16x8 wri = ldfrag(&smW[0 * 2048 + wb]);
            const bf16x8 wzi = ldfrag(&smW[1 * 2048 + wb]);
            const bf16x8 wni = ldfrag(&smW[2 * 2048 + wb]);
            const bf16x8 wrh = ldfrag(&smW[3 * 2048 + wb]);
            const bf16x8 wzh = ldfrag(&smW[4 * 2048 + wb]);
            const bf16x8 wnh = ldfrag(&smW[5 * 2048 + wb]);
            aR[cb] = MFMA(ah, wri, aR[cb]);
            aZ[cb] = MFMA(ah, wzi, aZ[cb]);
            aNI[cb] = MFMA(ah, wni, aNI[cb]);
            aNH[cb] = MFMA(hh, wnh, aNH[cb]);
            aR[cb] = MFMA(al, wri, aR[cb]);
            aZ[cb] = MFMA(al, wzi, aZ[cb]);
            aNI[cb] = MFMA(al, wni, aNI[cb]);
            aNH[cb] = MFMA(hl, wnh, aNH[cb]);
            aR[cb] = MFMA(hh, wrh, aR[cb]);
            aZ[cb] = MFMA(hh, wzh, aZ[cb]);
            aR[cb] = MFMA(hl, wrh, aR[cb]);
            aZ[cb] = MFMA(hl, wzh, aZ[cb]);
            if (fullsplit) {
                const size_t wr = (size_t)(c0 + cb * 16 + lm) * 256 + ks + lq * 8;
                aR[cb] = MFMA(ah, ldfrag(WihL + wr), aR[cb]);
                aR[cb] = MFMA(hh, ldfrag(WhhL + wr), aR[cb]);
                aZ[cb] = MFMA(ah, ldfrag(WihL + wr + 65536), aZ[cb]);
                aZ[cb] = MFMA(hh, ldfrag(WhhL + wr + 65536), aZ[cb]);
                aNI[cb] = MFMA(ah, ldfrag(WihL + wr + 131072), aNI[cb]);
                aNH[cb] = MFMA(hh, ldfrag(WhhL + wr + 131072), aNH[cb]);
            }
        }
        __syncthreads();
    }
#pragma unroll
    for (int cb = 0; cb < 4; ++cb) {
        const int col = c0 + cb * 16 + lm;
        const float rb = bsum[col];
        const float zb = bsum[256 + col];
        const float ib = bni[col];
        const float hb = bnh[col];
#pragma unroll
        for (int v = 0; v < 4; ++v) {
            const int row = r0 + w16 + lq * 4 + v;
            if (row < N) {
                const size_t off = (size_t)row * 256 + col;
                const float hold = bs2f(hoH[off]) + bs2f(hoL[off]);
                const float r = 1.f / (1.f + expf(-(aR[cb][v] + rb)));
                const float z = 1.f / (1.f + expf(-(aZ[cb][v] + zb)));
                const float nn = tanhf(aNI[cb][v] + ib + r * (aNH[cb][v] + hb));
                const float hv = (1.f - z) * nn + z * hold;
                const ushort hi = f2bs(hv);
                hnH[off] = hi;
                hnL[off] = f2bs(hv - bs2f(hi));
            }
        }
    }
}

// out[n] = sum_t relu(h[n,t]) * fc_w[t] + fc_b ; one 256-thread block per node
__global__ void final_k(const ushort* __restrict__ hH, const ushort* __restrict__ hL,
                        const void* fcw, const void* fcb,
                        void* out, const int* flags, int N) {
    const int n = blockIdx.x;
    const int t = threadIdx.x;
    const int isbf = flags[0];
    const size_t off = (size_t)n * HDIM + t;
    float v = fmaxf(bs2f(hH[off]) + bs2f(hL[off]), 0.f) * ldf(fcw, t, isbf);
#pragma unroll
    for (int offx = 32; offx >= 1; offx >>= 1) v += __shfl_down(v, offx);
    __shared__ float red[4];
    if ((t & 63) == 0) red[t >> 6] = v;
    __syncthreads();
    if (t == 0) {
        const float s = red[0] + red[1] + red[2] + red[3] + ldf(fcb, 0, isbf);
        if (isbf) ((__hip_bfloat16*)out)[n] = __float2bfloat16(s);
        else      ((float*)out)[n] = s;
    }
}

extern "C" void kernel_launch(void* const* d_in, const int* in_sizes, int n_in,
                              void* d_out, int out_size, void* d_ws, size_t ws_size,
                              hipStream_t stream) {
    const int H = HDIM;
    const int N = in_sizes[0] / H;       // 50000
    const int E = in_sizes[2];           // 800000
    const int L = in_sizes[3] / (H * H); // 5
    const size_t NH = (size_t)N * H;
    const int NB = (N + 255) / 256;

    char* base = (char*)d_ws;
    int*  flags = (int*)base;                         // 64 B
    char* regA  = base + 64;                          // NH*4 B (h planes / m)
    char* regB  = regA + NH * 4;                      // NH*4 B
    ushort* aggH = (ushort*)(regB + NH * 4);          // NH
    ushort* aggL = aggH + NH;                         // NH
    ushort* WtH  = aggL + NH;                         // L*65536
    ushort* WtL  = WtH + (size_t)L * 65536;
    ushort* WihH = WtL + (size_t)L * 65536;           // 196608
    ushort* WihL = WihH + 196608;
    ushort* WhhH = WihL + 196608;
    ushort* WhhL = WhhH + 196608;
    float* bsum  = (float*)(WhhL + 196608);           // 512
    float* bni   = bsum + 512;                        // 256
    float* bnh   = bni + 256;                         // 256
    int* ptr     = (int*)(bnh + 256);                 // N+1
    int* cursor  = ptr + (N + 1);                     // N
    int* bsumN   = cursor + N;                        // NB
    int* srcs    = bsumN + NB;                        // E
    float* wse   = (float*)(srcs + E);                // E
    // total ~= 165 MiB

    detect_k<<<dim3(1), dim3(64), 0, stream>>>(d_in[0], d_in[1], flags);
    conv_h0_k<<<dim3((unsigned)((NH + 255) / 256)), dim3(256), 0, stream>>>(
        d_in[0], (ushort*)regA, (ushort*)regA + NH, flags, NH);
    prep_k<<<dim3((L * 65536 + 255) / 256), dim3(256), 0, stream>>>(
        d_in[3], d_in[4], d_in[5], d_in[6], d_in[7],
        WtH, WtL, WihH, WihL, WhhH, WhhL, bsum, bni, bnh, flags, L);

    zero_int_k<<<dim3(NB), dim3(256), 0, stream>>>(cursor, N);
    count_k<<<dim3((E + 255) / 256), dim3(256), 0, stream>>>(d_in[1], cursor, flags, E);
    scan1_k<<<dim3(NB), dim3(256), 0, stream>>>(cursor, ptr, bsumN, N);
    scan2_k<<<dim3(1), dim3(256), 0, stream>>>(bsumN, NB);
    scan3_k<<<dim3(NB), dim3(256), 0, stream>>>(ptr, cursor, bsumN, N, E);
    fill_k<<<dim3((E + 255) / 256), dim3(256), 0, stream>>>(
        d_in[1], d_in[2], cursor, srcs, wse, flags, E);

    const dim3 blk(256);
    const int gm = (N + 63) / 64;
    char* regH = regA;  // current h (hi/lo planes)
    char* regM = regB;  // m (f32), later h_new planes
    for (int l = 0; l < L; ++l) {
        ushort* hH = (ushort*)regH;
        ushort* hL = hH + NH;
        mfma_gemm1_k<<<dim3(gm, 4), blk, 0, stream>>>(
            hH, hL, WtH + (size_t)l * 65536, WtL + (size_t)l * 65536,
            (float*)regM, flags, N);
        spmm_k<<<dim3((N + 3) / 4), blk, 0, stream>>>(
            (const float*)regM, ptr, srcs, wse, aggH, aggL, N);
        mfma_gates_k<<<dim3(gm, 4), blk, 0, stream>>>(
            aggH, aggL, hH, hL, WihH, WihL, WhhH, WhhL, bsum, bni, bnh,
            (ushort*)regM, (ushort*)regM + NH, flags, N);
        char* t = regH; regH = regM; regM = t;
    }
    final_k<<<dim3(N), blk, 0, stream>>>(
        (ushort*)regH, (ushort*)regH + NH, d_in[8], d_in[9], d_out, flags, N);
}